// Round 1
// baseline (1437.118 us; speedup 1.0000x reference)
//
#include <hip/hip_runtime.h>

#define DEV_INLINE __device__ __forceinline__

DEV_INLINE unsigned fencode(float f) {
  unsigned u = __float_as_uint(f);
  return (u & 0x80000000u) ? ~u : (u | 0x80000000u);
}
DEV_INLINE float fdecode(unsigned k) {
  return __uint_as_float((k & 0x80000000u) ? (k ^ 0x80000000u) : ~k);
}

// ---------------- prep: dis=1.0 (self loop), concat W1A..D and biases ----------
__global__ __launch_bounds__(256)
void prep_kernel(float* __restrict__ dis, float* __restrict__ Wcat, float* __restrict__ biascat,
                 const float* __restrict__ WA, const float* __restrict__ WB,
                 const float* __restrict__ WC, const float* __restrict__ WD,
                 const float* __restrict__ bA, const float* __restrict__ bB,
                 const float* __restrict__ bC, const float* __restrict__ bD,
                 int n5) {
  int i = blockIdx.x * 256 + threadIdx.x;
  if (i < n5) dis[i] = 1.0f;
  if (i < 128 * 512) {
    int k = i >> 9, col = i & 511, c = col >> 7, j = col & 127;
    const float* W = (c == 0) ? WA : (c == 1) ? WB : (c == 2) ? WC : WD;
    Wcat[i] = W[k * 128 + j];
  }
  if (i < 512) {
    int c = i >> 7, j = i & 127;
    const float* b = (c == 0) ? bA : (c == 1) ? bB : (c == 2) ? bC : bD;
    biascat[i] = b[j];
  }
}

// ---------------- degree accumulation (5 weight configs) + in-degree count ----
__global__ __launch_bounds__(256)
void deg_kernel(const int* __restrict__ ei, const float* __restrict__ eattr,
                float* __restrict__ dis, int* __restrict__ cnt, int n, int E) {
  int e = blockIdx.x * 256 + threadIdx.x;
  if (e >= E) return;
  int d = ei[E + e];  // dst row
  float4 w = ((const float4*)eattr)[e];
  atomicAdd(&dis[0 * n + d], w.x);
  atomicAdd(&dis[1 * n + d], w.y);
  atomicAdd(&dis[2 * n + d], w.z);
  atomicAdd(&dis[3 * n + d], w.w);
  atomicAdd(&dis[4 * n + d], 1.0f);
  atomicAdd(&cnt[d], 1);
}

__global__ __launch_bounds__(256)
void rsqrt_kernel(float* __restrict__ dis, int n5) {
  int i = blockIdx.x * 256 + threadIdx.x;
  if (i < n5) dis[i] = 1.0f / sqrtf(dis[i]);  // deg >= 1 always (self loop)
}

// ---------------- single-block exclusive scan (n=50000) -----------------------
__global__ __launch_bounds__(1024)
void scan_kernel(const int* __restrict__ cnt, int* __restrict__ rowptr,
                 int* __restrict__ rowwork, int n) {
  __shared__ int sdata[1024];
  __shared__ int carry_s;
  if (threadIdx.x == 0) carry_s = 0;
  __syncthreads();
  for (int base = 0; base < n; base += 1024) {
    int i = base + (int)threadIdx.x;
    int v = (i < n) ? cnt[i] : 0;
    sdata[threadIdx.x] = v;
    __syncthreads();
    for (int off = 1; off < 1024; off <<= 1) {
      int t = (threadIdx.x >= (unsigned)off) ? sdata[threadIdx.x - off] : 0;
      __syncthreads();
      sdata[threadIdx.x] += t;
      __syncthreads();
    }
    int excl = sdata[threadIdx.x] - v;
    int c = carry_s;
    if (i < n) { rowptr[i] = c + excl; rowwork[i] = c + excl; }
    __syncthreads();
    if (threadIdx.x == 1023) carry_s = c + sdata[1023];
    __syncthreads();
  }
  if (threadIdx.x == 0) rowptr[n] = carry_s;
}

// ---------------- CSR fill ----------------------------------------------------
__global__ __launch_bounds__(256)
void fill_kernel(const int* __restrict__ ei, int* __restrict__ rowwork,
                 int* __restrict__ csr, int E) {
  int e = blockIdx.x * 256 + threadIdx.x;
  if (e >= E) return;
  int d = ei[E + e];
  int pos = atomicAdd(&rowwork[d], 1);
  csr[pos] = e;
}

// ---------------- fp32 tiled GEMM: C[MxN] = A[MxK] @ B[KxN] -------------------
// 128x128 block tile, BK=8, 8x8 per thread, 256 threads.
__global__ __launch_bounds__(256)
void gemm_kernel(const float* __restrict__ A, const float* __restrict__ B,
                 float* __restrict__ C, int M, int N, int K) {
  __shared__ float As[8][132];   // [k][m], padded
  __shared__ float Bs[8][128];   // [k][n]
  int tid = threadIdx.x;
  int tx = tid & 15, ty = tid >> 4;
  int row0 = blockIdx.x * 128, col0 = blockIdx.y * 128;
  float acc[8][8];
#pragma unroll
  for (int i = 0; i < 8; ++i)
#pragma unroll
    for (int j = 0; j < 8; ++j) acc[i][j] = 0.0f;

  int arow = tid >> 1, ak = (tid & 1) * 4;      // A: 128 rows x 8 k, float4 along k
  int brow = tid >> 5, bcol = (tid & 31) * 4;   // B: 8 k x 128 n, float4 along n
  int nk = K >> 3;
  for (int kt = 0; kt < nk; ++kt) {
    int k0 = kt << 3;
    float4 av = make_float4(0.f, 0.f, 0.f, 0.f);
    int ga = row0 + arow;
    if (ga < M) av = *(const float4*)&A[(size_t)ga * K + k0 + ak];
    float4 bv = *(const float4*)&B[(size_t)(k0 + brow) * N + col0 + bcol];
    __syncthreads();
    As[ak + 0][arow] = av.x;
    As[ak + 1][arow] = av.y;
    As[ak + 2][arow] = av.z;
    As[ak + 3][arow] = av.w;
    *(float4*)&Bs[brow][bcol] = bv;
    __syncthreads();
#pragma unroll
    for (int kk = 0; kk < 8; ++kk) {
      float4 a0 = *(const float4*)&As[kk][ty * 8];
      float4 a1 = *(const float4*)&As[kk][ty * 8 + 4];
      float4 b0 = *(const float4*)&Bs[kk][tx * 8];
      float4 b1 = *(const float4*)&Bs[kk][tx * 8 + 4];
      float a[8] = {a0.x, a0.y, a0.z, a0.w, a1.x, a1.y, a1.z, a1.w};
      float b[8] = {b0.x, b0.y, b0.z, b0.w, b1.x, b1.y, b1.z, b1.w};
#pragma unroll
      for (int i = 0; i < 8; ++i)
#pragma unroll
        for (int j = 0; j < 8; ++j) acc[i][j] += a[i] * b[j];
    }
  }
#pragma unroll
  for (int i = 0; i < 8; ++i) {
    int r = row0 + ty * 8 + i;
    if (r < M) {
#pragma unroll
      for (int j = 0; j < 8; j += 4) {
        float4 v = make_float4(acc[i][j], acc[i][j + 1], acc[i][j + 2], acc[i][j + 3]);
        *(float4*)&C[(size_t)r * N + col0 + tx * 8 + j] = v;
      }
    }
  }
}

// ---------------- layer-1 aggregation: 4 convs, D_out=4*128 -------------------
// one block (128 thr) per node; thread t handles float4 at column 4t; conv c = t>>5
__global__ __launch_bounds__(128)
void agg4_kernel(const float* __restrict__ hc, float* __restrict__ out,
                 const int* __restrict__ rowptr, const int* __restrict__ csr,
                 const int* __restrict__ ei, const float* __restrict__ eattr,
                 const float* __restrict__ dis, const float* __restrict__ bias,
                 int n) {
  int d = blockIdx.x;
  int t = threadIdx.x;
  int c = t >> 5;
  float dcd = dis[c * n + d];
  const float4* hc4 = (const float4*)hc;
  float4 v = hc4[(size_t)d * 128 + t];
  float sw = dcd * dcd;  // self loop, weight 1
  float ax = v.x * sw, ay = v.y * sw, az = v.z * sw, aw = v.w * sw;
  int beg = rowptr[d], end = rowptr[d + 1];
  for (int i = beg; i < end; ++i) {
    int e = csr[i];
    int s = ei[e];
    float w = eattr[(size_t)e * 4 + c];
    float nrm = dis[c * n + s] * w * dcd;
    float4 h = hc4[(size_t)s * 128 + t];
    ax += h.x * nrm; ay += h.y * nrm; az += h.z * nrm; aw += h.w * nrm;
  }
  float4 b = ((const float4*)bias)[t];
  ax = fmaxf(ax + b.x, 0.0f);
  ay = fmaxf(ay + b.y, 0.0f);
  az = fmaxf(az + b.z, 0.0f);
  aw = fmaxf(aw + b.w, 0.0f);
  ((float4*)out)[(size_t)d * 128 + t] = make_float4(ax, ay, az, aw);
}

// ---------------- layers 2/3 aggregation (edge weight = 1) --------------------
// 64 threads per node, VEC floats each (VEC=4 -> D=256, VEC=2 -> D=128)
template <int VEC, bool RELU>
__global__ __launch_bounds__(64)
void agg1_kernel(const float* __restrict__ hin, float* __restrict__ out,
                 const int* __restrict__ rowptr, const int* __restrict__ csr,
                 const int* __restrict__ ei, const float* __restrict__ dis1,
                 const float* __restrict__ bias, int n) {
  constexpr int DOUT = VEC * 64;
  int d = blockIdx.x;
  int t = threadIdx.x;
  float dd = dis1[d];
  float acc[VEC];
  {
    float sw = dd * dd;
#pragma unroll
    for (int k = 0; k < VEC; ++k) acc[k] = hin[(size_t)d * DOUT + t * VEC + k] * sw;
  }
  int beg = rowptr[d], end = rowptr[d + 1];
  for (int i = beg; i < end; ++i) {
    int e = csr[i];
    int s = ei[e];
    float nrm = dis1[s] * dd;
    if (VEC == 4) {
      float4 h = *(const float4*)&hin[(size_t)s * DOUT + t * 4];
      acc[0] += h.x * nrm; acc[1] += h.y * nrm;
      acc[2 % VEC] += h.z * nrm; acc[3 % VEC] += h.w * nrm;
    } else {
      float2 h = *(const float2*)&hin[(size_t)s * DOUT + t * 2];
      acc[0] += h.x * nrm; acc[1 % VEC] += h.y * nrm;
    }
  }
#pragma unroll
  for (int k = 0; k < VEC; ++k) {
    float r = acc[k] + bias[t * VEC + k];
    if (RELU) r = fmaxf(r, 0.0f);
    out[(size_t)d * DOUT + t * VEC + k] = r;
  }
}

// ---------------- per-graph node counts ---------------------------------------
__global__ __launch_bounds__(256)
void count_kernel(const int* __restrict__ batch, int* __restrict__ gcnt, int n) {
  int i = blockIdx.x * 256 + threadIdx.x;
  if (i < n) atomicAdd(&gcnt[batch[i]], 1);
}

// ---------------- pooling: per-graph sum + max (encoded uint) -----------------
__global__ __launch_bounds__(128)
void pool_kernel(const float* __restrict__ h3, const int* __restrict__ batch,
                 float* __restrict__ gsum, unsigned* __restrict__ gmax, int n) {
  int c = threadIdx.x;
  int start = blockIdx.x * 32;
  int end = min(start + 32, n);
  int curg = -1;
  float s = 0.0f, m = -3.402823466e38f;
  for (int i = start; i < end; ++i) {
    int g = batch[i];  // sorted; wave-uniform
    if (g != curg) {
      if (curg >= 0) {
        atomicAdd(&gsum[curg * 128 + c], s);
        atomicMax(&gmax[curg * 128 + c], fencode(m));
      }
      curg = g; s = 0.0f; m = -3.402823466e38f;
    }
    float v = h3[(size_t)i * 128 + c];
    s += v;
    m = fmaxf(m, v);
  }
  if (curg >= 0) {
    atomicAdd(&gsum[curg * 128 + c], s);
    atomicMax(&gmax[curg * 128 + c], fencode(m));
  }
}

// ---------------- final MLP: logits = relu(g@Wm1+bm1)@Wm2+bm2 -----------------
__global__ __launch_bounds__(512)
void mlp_kernel(const float* __restrict__ gsum, const unsigned* __restrict__ gmax,
                const int* __restrict__ gcnt, const float* __restrict__ Wm1,
                const float* __restrict__ bm1, const float* __restrict__ Wm2,
                const float* __restrict__ bm2, float* __restrict__ out) {
  __shared__ float hid[64][8];
  int t = threadIdx.x;
  int gi = t >> 3, u = t & 7;
  int cnt = gcnt[gi];
  float inv = 1.0f / fmaxf((float)cnt, 1.0f);
  float s = bm1[u];
  for (int k = 0; k < 128; ++k) {
    float mean = gsum[gi * 128 + k] * inv;
    s += mean * Wm1[k * 8 + u];
  }
  for (int k = 0; k < 128; ++k) {
    float mx = (cnt > 0) ? fdecode(gmax[gi * 128 + k]) : 0.0f;
    s += mx * Wm1[(128 + k) * 8 + u];
  }
  hid[gi][u] = fmaxf(s, 0.0f);
  __syncthreads();
  if (t < 128) {
    int g2 = t >> 1, o = t & 1;
    float s2 = bm2[o];
#pragma unroll
    for (int uu = 0; uu < 8; ++uu) s2 += hid[g2][uu] * Wm2[uu * 2 + o];
    out[g2 * 2 + o] = s2;
  }
}

extern "C" void kernel_launch(void* const* d_in, const int* in_sizes, int n_in,
                              void* d_out, int out_size, void* d_ws, size_t ws_size,
                              hipStream_t stream) {
  const float* x     = (const float*)d_in[0];
  const int*   ei    = (const int*)d_in[1];
  const float* eattr = (const float*)d_in[2];
  const int*   batch = (const int*)d_in[3];
  const float* W1A = (const float*)d_in[4],  *b1A = (const float*)d_in[5];
  const float* W1B = (const float*)d_in[6],  *b1B = (const float*)d_in[7];
  const float* W1C = (const float*)d_in[8],  *b1C = (const float*)d_in[9];
  const float* W1D = (const float*)d_in[10], *b1D = (const float*)d_in[11];
  const float* W2  = (const float*)d_in[12], *b2  = (const float*)d_in[13];
  const float* W3  = (const float*)d_in[14], *b3  = (const float*)d_in[15];
  const float* Wm1 = (const float*)d_in[16], *bm1 = (const float*)d_in[17];
  const float* Wm2 = (const float*)d_in[18], *bm2 = (const float*)d_in[19];
  float* out = (float*)d_out;

  const int n = in_sizes[0] / 128;
  const int E = in_sizes[1] / 2;
  const int n5 = 5 * n;

  char* ws = (char*)d_ws;
  size_t off = 0;
  auto alloc = [&](size_t bytes) -> void* {
    void* p = ws + off;
    off += (bytes + 255) & ~(size_t)255;
    return p;
  };

  float*    dis     = (float*)alloc((size_t)n5 * 4);
  int*      rowptr  = (int*)alloc(((size_t)n + 1) * 4);
  int*      rowwork = (int*)alloc((size_t)n * 4);
  // ---- zero block start ----
  size_t zoff = off;
  int*      cnt     = (int*)alloc((size_t)n * 4);
  float*    gsum    = (float*)alloc(64 * 128 * 4);
  unsigned* gmax    = (unsigned*)alloc(64 * 128 * 4);
  int*      gcnt    = (int*)alloc(64 * 4);
  size_t zbytes = off - zoff;
  // ---- zero block end ----
  int*      csr     = (int*)alloc((size_t)E * 4);
  float*    Wcat    = (float*)alloc(128 * 512 * 4);
  float*    biascat = (float*)alloc(512 * 4);
  float*    hc      = (float*)alloc((size_t)n * 512 * 4);  // also h2pre/h2
  float*    h1      = (float*)alloc((size_t)n * 512 * 4);  // also h3pre/h3
  float*    h2pre = hc;
  float*    h2    = hc + (size_t)n * 256;
  float*    h3pre = h1;
  float*    h3    = h1 + (size_t)n * 128;

  hipMemsetAsync(ws + zoff, 0, zbytes, stream);

  int gprep = (max(n5, 128 * 512) + 255) / 256;
  prep_kernel<<<gprep, 256, 0, stream>>>(dis, Wcat, biascat, W1A, W1B, W1C, W1D,
                                         b1A, b1B, b1C, b1D, n5);
  deg_kernel<<<(E + 255) / 256, 256, 0, stream>>>(ei, eattr, dis, cnt, n, E);
  rsqrt_kernel<<<(n5 + 255) / 256, 256, 0, stream>>>(dis, n5);
  scan_kernel<<<1, 1024, 0, stream>>>(cnt, rowptr, rowwork, n);
  fill_kernel<<<(E + 255) / 256, 256, 0, stream>>>(ei, rowwork, csr, E);
  count_kernel<<<(n + 255) / 256, 256, 0, stream>>>(batch, gcnt, n);

  int mblocks = (n + 127) / 128;
  // layer 1: hc = x @ Wcat  [n,512]
  gemm_kernel<<<dim3(mblocks, 4), 256, 0, stream>>>(x, Wcat, hc, n, 512, 128);
  agg4_kernel<<<n, 128, 0, stream>>>(hc, h1, rowptr, csr, ei, eattr, dis, biascat, n);
  // layer 2: h2pre = h1 @ W2 [n,256]
  gemm_kernel<<<dim3(mblocks, 2), 256, 0, stream>>>(h1, W2, h2pre, n, 256, 512);
  agg1_kernel<4, true><<<n, 64, 0, stream>>>(h2pre, h2, rowptr, csr, ei, dis + (size_t)4 * n, b2, n);
  // layer 3: h3pre = h2 @ W3 [n,128]
  gemm_kernel<<<dim3(mblocks, 1), 256, 0, stream>>>(h2, W3, h3pre, n, 128, 256);
  agg1_kernel<2, false><<<n, 64, 0, stream>>>(h3pre, h3, rowptr, csr, ei, dis + (size_t)4 * n, b3, n);

  pool_kernel<<<(n + 31) / 32, 128, 0, stream>>>(h3, batch, gsum, gmax, n);
  mlp_kernel<<<1, 512, 0, stream>>>(gsum, gmax, gcnt, Wm1, bm1, Wm2, bm2, out);
}

// Round 2
// 902.162 us; speedup vs baseline: 1.5930x; 1.5930x over previous
//
#include <hip/hip_runtime.h>

#define DEV_INLINE __device__ __forceinline__

DEV_INLINE unsigned fencode(float f) {
  unsigned u = __float_as_uint(f);
  return (u & 0x80000000u) ? ~u : (u | 0x80000000u);
}
DEV_INLINE float fdecode(unsigned k) {
  return __uint_as_float((k & 0x80000000u) ? (k ^ 0x80000000u) : ~k);
}

// ---------------- prep: pack W1A..D -> Wcat[4][128][128], biases -> biascat[512]
__global__ __launch_bounds__(256)
void prep_kernel(float* __restrict__ Wcat, float* __restrict__ biascat,
                 const float* __restrict__ WA, const float* __restrict__ WB,
                 const float* __restrict__ WC, const float* __restrict__ WD,
                 const float* __restrict__ bA, const float* __restrict__ bB,
                 const float* __restrict__ bC, const float* __restrict__ bD) {
  int i = blockIdx.x * 256 + threadIdx.x;
  if (i < 4 * 128 * 128) {
    int c = i >> 14, idx = i & 16383;
    const float* W = (c == 0) ? WA : (c == 1) ? WB : (c == 2) ? WC : WD;
    Wcat[i] = W[idx];
  }
  if (i < 512) {
    int c = i >> 7, j = i & 127;
    const float* b = (c == 0) ? bA : (c == 1) ? bB : (c == 2) ? bC : bD;
    biascat[i] = b[j];
  }
}

// ---------------- in-degree histogram ----------------------------------------
__global__ __launch_bounds__(256)
void hist_kernel(const int* __restrict__ ei, int* __restrict__ cnt, int E) {
  int e = blockIdx.x * 256 + threadIdx.x;
  if (e < E) atomicAdd(&cnt[ei[E + e]], 1);
}

// ---------------- 3-level exclusive scan -------------------------------------
__global__ __launch_bounds__(256)
void scan1_kernel(const int* __restrict__ cnt, int* __restrict__ local,
                  int* __restrict__ bsum, int n) {
  __shared__ int s[256];
  int tid = threadIdx.x;
  int i = blockIdx.x * 256 + tid;
  int v = (i < n) ? cnt[i] : 0;
  s[tid] = v;
  __syncthreads();
#pragma unroll
  for (int off = 1; off < 256; off <<= 1) {
    int t = (tid >= off) ? s[tid - off] : 0;
    __syncthreads();
    s[tid] += t;
    __syncthreads();
  }
  if (i < n) local[i] = s[tid] - v;
  if (tid == 255) bsum[blockIdx.x] = s[255];
}

__global__ __launch_bounds__(256)
void scan2_kernel(int* __restrict__ bsum, int nb) {
  __shared__ int s[256];
  int tid = threadIdx.x;
  int v = (tid < nb) ? bsum[tid] : 0;
  s[tid] = v;
  __syncthreads();
#pragma unroll
  for (int off = 1; off < 256; off <<= 1) {
    int t = (tid >= off) ? s[tid - off] : 0;
    __syncthreads();
    s[tid] += t;
    __syncthreads();
  }
  if (tid < nb) bsum[tid] = s[tid] - v;  // exclusive
}

__global__ __launch_bounds__(256)
void scan3_kernel(const int* __restrict__ local, const int* __restrict__ bsum,
                  int* __restrict__ rowptr, int* __restrict__ rowwork, int n, int E) {
  int i = blockIdx.x * 256 + threadIdx.x;
  if (i < n) {
    int rp = local[i] + bsum[blockIdx.x];
    rowptr[i] = rp;
    rowwork[i] = rp;
  }
  if (i == 0) rowptr[n] = E;
}

// ---------------- CSR fill ----------------------------------------------------
__global__ __launch_bounds__(256)
void fill_kernel(const int* __restrict__ ei, int* __restrict__ rowwork,
                 int* __restrict__ csr, int E) {
  int e = blockIdx.x * 256 + threadIdx.x;
  if (e >= E) return;
  int d = ei[E + e];
  int pos = atomicAdd(&rowwork[d], 1);
  csr[pos] = e;
}

// ---------------- degrees from CSR (node-centric, fused rsqrt) ----------------
__global__ __launch_bounds__(256)
void degcsr_kernel(const int* __restrict__ rowptr, const int* __restrict__ csr,
                   const float* __restrict__ eattr, float* __restrict__ dis, int n) {
  int d = blockIdx.x * 256 + threadIdx.x;
  if (d >= n) return;
  int beg = rowptr[d], end = rowptr[d + 1];
  float s0 = 1.f, s1 = 1.f, s2 = 1.f, s3 = 1.f;  // self-loop weight 1
  for (int i = beg; i < end; ++i) {
    int e = csr[i];
    float4 w = ((const float4*)eattr)[e];
    s0 += w.x; s1 += w.y; s2 += w.z; s3 += w.w;
  }
  dis[d]         = 1.0f / sqrtf(s0);
  dis[n + d]     = 1.0f / sqrtf(s1);
  dis[2 * n + d] = 1.0f / sqrtf(s2);
  dis[3 * n + d] = 1.0f / sqrtf(s3);
  dis[4 * n + d] = 1.0f / sqrtf(1.0f + (float)(end - beg));
}

// ---------------- layer-1 aggregation on raw x (before GEMM) ------------------
// one block (64 thr) per node; thread t holds float2 of 128 cols; 4 accumulators
__global__ __launch_bounds__(64)
void agg4x_kernel(const float* __restrict__ x, float* __restrict__ xa,
                  const int* __restrict__ rowptr, const int* __restrict__ csr,
                  const int* __restrict__ ei, const float* __restrict__ eattr,
                  const float* __restrict__ dis, int n) {
  int d = blockIdx.x;
  int t = threadIdx.x;
  float dc0 = dis[d], dc1 = dis[n + d], dc2 = dis[2 * n + d], dc3 = dis[3 * n + d];
  const float2* x2 = (const float2*)x;
  float2 xv = x2[(size_t)d * 64 + t];
  float a0x = xv.x * dc0 * dc0, a0y = xv.y * dc0 * dc0;
  float a1x = xv.x * dc1 * dc1, a1y = xv.y * dc1 * dc1;
  float a2x = xv.x * dc2 * dc2, a2y = xv.y * dc2 * dc2;
  float a3x = xv.x * dc3 * dc3, a3y = xv.y * dc3 * dc3;
  int beg = rowptr[d], end = rowptr[d + 1];
  for (int i = beg; i < end; ++i) {
    int e = csr[i];
    int s = ei[e];
    float4 w = ((const float4*)eattr)[e];
    float n0 = dis[s] * w.x * dc0;
    float n1 = dis[n + s] * w.y * dc1;
    float n2 = dis[2 * n + s] * w.z * dc2;
    float n3 = dis[3 * n + s] * w.w * dc3;
    float2 h = x2[(size_t)s * 64 + t];
    a0x += h.x * n0; a0y += h.y * n0;
    a1x += h.x * n1; a1y += h.y * n1;
    a2x += h.x * n2; a2y += h.y * n2;
    a3x += h.x * n3; a3y += h.y * n3;
  }
  float2* xa2 = (float2*)xa;
  size_t nd64 = (size_t)n * 64;
  xa2[(size_t)d * 64 + t]            = make_float2(a0x, a0y);
  xa2[nd64 + (size_t)d * 64 + t]     = make_float2(a1x, a1y);
  xa2[2 * nd64 + (size_t)d * 64 + t] = make_float2(a2x, a2y);
  xa2[3 * nd64 + (size_t)d * 64 + t] = make_float2(a3x, a3y);
}

// ---------------- fp32 tiled GEMM body: C[MxN] = A[MxK] @ B[KxN] --------------
// 128x128 block tile, BK=8, 8x8 per thread, 256 threads. A lda=K, B ldb=N.
template <bool RELU, bool BIAS>
DEV_INLINE void gemm_body(const float* __restrict__ A, const float* __restrict__ B,
                          const float* __restrict__ bias, float* __restrict__ C,
                          int M, int N, int K, int ldc) {
  __shared__ float As[8][132];   // [k][m], padded
  __shared__ float Bs[8][128];   // [k][n]
  int tid = threadIdx.x;
  int tx = tid & 15, ty = tid >> 4;
  int row0 = blockIdx.x * 128, col0 = blockIdx.y * 128;
  float acc[8][8];
#pragma unroll
  for (int i = 0; i < 8; ++i)
#pragma unroll
    for (int j = 0; j < 8; ++j) acc[i][j] = 0.0f;

  int arow = tid >> 1, ak = (tid & 1) * 4;      // A: 128 rows x 8 k, float4 along k
  int brow = tid >> 5, bcol = (tid & 31) * 4;   // B: 8 k x 128 n, float4 along n
  int nk = K >> 3;
  for (int kt = 0; kt < nk; ++kt) {
    int k0 = kt << 3;
    float4 av = make_float4(0.f, 0.f, 0.f, 0.f);
    int ga = row0 + arow;
    if (ga < M) av = *(const float4*)&A[(size_t)ga * K + k0 + ak];
    float4 bv = *(const float4*)&B[(size_t)(k0 + brow) * N + col0 + bcol];
    __syncthreads();
    As[ak + 0][arow] = av.x;
    As[ak + 1][arow] = av.y;
    As[ak + 2][arow] = av.z;
    As[ak + 3][arow] = av.w;
    *(float4*)&Bs[brow][bcol] = bv;
    __syncthreads();
#pragma unroll
    for (int kk = 0; kk < 8; ++kk) {
      float4 a0 = *(const float4*)&As[kk][ty * 8];
      float4 a1 = *(const float4*)&As[kk][ty * 8 + 4];
      float4 b0 = *(const float4*)&Bs[kk][tx * 8];
      float4 b1 = *(const float4*)&Bs[kk][tx * 8 + 4];
      float a[8] = {a0.x, a0.y, a0.z, a0.w, a1.x, a1.y, a1.z, a1.w};
      float b[8] = {b0.x, b0.y, b0.z, b0.w, b1.x, b1.y, b1.z, b1.w};
#pragma unroll
      for (int i = 0; i < 8; ++i)
#pragma unroll
        for (int j = 0; j < 8; ++j) acc[i][j] += a[i] * b[j];
    }
  }
#pragma unroll
  for (int i = 0; i < 8; ++i) {
    int r = row0 + ty * 8 + i;
    if (r < M) {
#pragma unroll
      for (int j = 0; j < 8; j += 4) {
        float4 v = make_float4(acc[i][j], acc[i][j + 1], acc[i][j + 2], acc[i][j + 3]);
        if (BIAS) {
          int col = col0 + tx * 8 + j;
          v.x += bias[col]; v.y += bias[col + 1]; v.z += bias[col + 2]; v.w += bias[col + 3];
        }
        if (RELU) {
          v.x = fmaxf(v.x, 0.f); v.y = fmaxf(v.y, 0.f);
          v.z = fmaxf(v.z, 0.f); v.w = fmaxf(v.w, 0.f);
        }
        *(float4*)&C[(size_t)r * ldc + col0 + tx * 8 + j] = v;
      }
    }
  }
}

__global__ __launch_bounds__(256)
void gemm_kernel(const float* __restrict__ A, const float* __restrict__ B,
                 float* __restrict__ C, int M, int N, int K, int ldc) {
  gemm_body<false, false>(A, B, nullptr, C, M, N, K, ldc);
}

// layer-1 batched GEMM: z = conv index; h1[:, z*128:(z+1)*128] = relu(xa_z @ W_z + b_z)
__global__ __launch_bounds__(256)
void gemm_l1_kernel(const float* __restrict__ xa, const float* __restrict__ Wcat,
                    const float* __restrict__ biascat, float* __restrict__ h1, int M) {
  int z = blockIdx.z;
  gemm_body<true, true>(xa + (size_t)z * M * 128, Wcat + z * 128 * 128,
                        biascat + z * 128, h1 + z * 128, M, 128, 128, 512);
}

// ---------------- layers 2/3 aggregation (edge weight = 1) --------------------
template <int VEC, bool RELU>
__global__ __launch_bounds__(64)
void agg1_kernel(const float* __restrict__ hin, float* __restrict__ out,
                 const int* __restrict__ rowptr, const int* __restrict__ csr,
                 const int* __restrict__ ei, const float* __restrict__ dis1,
                 const float* __restrict__ bias, int n) {
  constexpr int DOUT = VEC * 64;
  int d = blockIdx.x;
  int t = threadIdx.x;
  float dd = dis1[d];
  float acc[VEC];
  {
    float sw = dd * dd;
#pragma unroll
    for (int k = 0; k < VEC; ++k) acc[k] = hin[(size_t)d * DOUT + t * VEC + k] * sw;
  }
  int beg = rowptr[d], end = rowptr[d + 1];
  for (int i = beg; i < end; ++i) {
    int e = csr[i];
    int s = ei[e];
    float nrm = dis1[s] * dd;
    if (VEC == 4) {
      float4 h = *(const float4*)&hin[(size_t)s * DOUT + t * 4];
      acc[0] += h.x * nrm; acc[1] += h.y * nrm;
      acc[2 % VEC] += h.z * nrm; acc[3 % VEC] += h.w * nrm;
    } else {
      float2 h = *(const float2*)&hin[(size_t)s * DOUT + t * 2];
      acc[0] += h.x * nrm; acc[1 % VEC] += h.y * nrm;
    }
  }
#pragma unroll
  for (int k = 0; k < VEC; ++k) {
    float r = acc[k] + bias[t * VEC + k];
    if (RELU) r = fmaxf(r, 0.0f);
    out[(size_t)d * DOUT + t * VEC + k] = r;
  }
}

// ---------------- pooling: per-graph sum + max (encoded uint) -----------------
__global__ __launch_bounds__(128)
void pool_kernel(const float* __restrict__ h3, const int* __restrict__ batch,
                 float* __restrict__ gsum, unsigned* __restrict__ gmax, int n) {
  int c = threadIdx.x;
  int start = blockIdx.x * 32;
  int end = min(start + 32, n);
  int curg = -1;
  float s = 0.0f, m = -3.402823466e38f;
  for (int i = start; i < end; ++i) {
    int g = batch[i];  // sorted; wave-uniform
    if (g != curg) {
      if (curg >= 0) {
        atomicAdd(&gsum[curg * 128 + c], s);
        atomicMax(&gmax[curg * 128 + c], fencode(m));
      }
      curg = g; s = 0.0f; m = -3.402823466e38f;
    }
    float v = h3[(size_t)i * 128 + c];
    s += v;
    m = fmaxf(m, v);
  }
  if (curg >= 0) {
    atomicAdd(&gsum[curg * 128 + c], s);
    atomicMax(&gmax[curg * 128 + c], fencode(m));
  }
}

// ---------------- final MLP; per-graph counts via binary search ---------------
__global__ __launch_bounds__(512)
void mlp_kernel(const float* __restrict__ gsum, const unsigned* __restrict__ gmax,
                const int* __restrict__ batch, int n, const float* __restrict__ Wm1,
                const float* __restrict__ bm1, const float* __restrict__ Wm2,
                const float* __restrict__ bm2, float* __restrict__ out) {
  __shared__ float hid[64][8];
  int t = threadIdx.x;
  int gi = t >> 3, u = t & 7;
  auto lb = [&](int key) {
    int lo = 0, hi = n;
    while (lo < hi) {
      int mid = (lo + hi) >> 1;
      if (batch[mid] < key) lo = mid + 1; else hi = mid;
    }
    return lo;
  };
  int cnt = lb(gi + 1) - lb(gi);
  float inv = 1.0f / fmaxf((float)cnt, 1.0f);
  float s = bm1[u];
  for (int k = 0; k < 128; ++k) {
    float mean = gsum[gi * 128 + k] * inv;
    s += mean * Wm1[k * 8 + u];
  }
  for (int k = 0; k < 128; ++k) {
    float mx = (cnt > 0) ? fdecode(gmax[gi * 128 + k]) : 0.0f;
    s += mx * Wm1[(128 + k) * 8 + u];
  }
  hid[gi][u] = fmaxf(s, 0.0f);
  __syncthreads();
  if (t < 128) {
    int g2 = t >> 1, o = t & 1;
    float s2 = bm2[o];
#pragma unroll
    for (int uu = 0; uu < 8; ++uu) s2 += hid[g2][uu] * Wm2[uu * 2 + o];
    out[g2 * 2 + o] = s2;
  }
}

extern "C" void kernel_launch(void* const* d_in, const int* in_sizes, int n_in,
                              void* d_out, int out_size, void* d_ws, size_t ws_size,
                              hipStream_t stream) {
  const float* x     = (const float*)d_in[0];
  const int*   ei    = (const int*)d_in[1];
  const float* eattr = (const float*)d_in[2];
  const int*   batch = (const int*)d_in[3];
  const float* W1A = (const float*)d_in[4],  *b1A = (const float*)d_in[5];
  const float* W1B = (const float*)d_in[6],  *b1B = (const float*)d_in[7];
  const float* W1C = (const float*)d_in[8],  *b1C = (const float*)d_in[9];
  const float* W1D = (const float*)d_in[10], *b1D = (const float*)d_in[11];
  const float* W2  = (const float*)d_in[12], *b2  = (const float*)d_in[13];
  const float* W3  = (const float*)d_in[14], *b3  = (const float*)d_in[15];
  const float* Wm1 = (const float*)d_in[16], *bm1 = (const float*)d_in[17];
  const float* Wm2 = (const float*)d_in[18], *bm2 = (const float*)d_in[19];
  float* out = (float*)d_out;

  const int n = in_sizes[0] / 128;
  const int E = in_sizes[1] / 2;

  char* ws = (char*)d_ws;
  size_t off = 0;
  auto alloc = [&](size_t bytes) -> void* {
    void* p = ws + off;
    off += (bytes + 255) & ~(size_t)255;
    return p;
  };

  float*    dis     = (float*)alloc((size_t)5 * n * 4);
  int*      rowptr  = (int*)alloc(((size_t)n + 1) * 4);
  int*      rowwork = (int*)alloc((size_t)n * 4);
  int*      local   = (int*)alloc((size_t)n * 4);
  int*      bsum    = (int*)alloc(256 * 4);
  // ---- zero block start ----
  size_t zoff = off;
  int*      cnt     = (int*)alloc((size_t)n * 4);
  float*    gsum    = (float*)alloc(64 * 128 * 4);
  unsigned* gmax    = (unsigned*)alloc(64 * 128 * 4);
  size_t zbytes = off - zoff;
  // ---- zero block end ----
  int*      csr     = (int*)alloc((size_t)E * 4);
  float*    Wcat    = (float*)alloc(4 * 128 * 128 * 4);
  float*    biascat = (float*)alloc(512 * 4);
  float*    xa      = (float*)alloc((size_t)n * 512 * 4);  // 4x[n,128]; reused as h2pre/h2
  float*    h1      = (float*)alloc((size_t)n * 512 * 4);  // [n,512]; reused as h3pre/h3
  float*    h2pre = xa;
  float*    h2    = xa + (size_t)n * 256;
  float*    h3pre = h1;
  float*    h3    = h1 + (size_t)n * 128;

  hipMemsetAsync(ws + zoff, 0, zbytes, stream);

  prep_kernel<<<(4 * 128 * 128 + 255) / 256, 256, 0, stream>>>(
      Wcat, biascat, W1A, W1B, W1C, W1D, b1A, b1B, b1C, b1D);

  int nb = (n + 255) / 256;
  hist_kernel<<<(E + 255) / 256, 256, 0, stream>>>(ei, cnt, E);
  scan1_kernel<<<nb, 256, 0, stream>>>(cnt, local, bsum, n);
  scan2_kernel<<<1, 256, 0, stream>>>(bsum, nb);
  scan3_kernel<<<nb, 256, 0, stream>>>(local, bsum, rowptr, rowwork, n, E);
  fill_kernel<<<(E + 255) / 256, 256, 0, stream>>>(ei, rowwork, csr, E);
  degcsr_kernel<<<(n + 255) / 256, 256, 0, stream>>>(rowptr, csr, eattr, dis, n);

  int mblocks = (n + 127) / 128;
  // layer 1: aggregate x (4 norms), then 4 fused GEMM+bias+relu into h1[n,512]
  agg4x_kernel<<<n, 64, 0, stream>>>(x, xa, rowptr, csr, ei, eattr, dis, n);
  gemm_l1_kernel<<<dim3(mblocks, 1, 4), 256, 0, stream>>>(xa, Wcat, biascat, h1, n);
  // layer 2: h2pre = h1 @ W2 [n,256]; agg+bias+relu
  gemm_kernel<<<dim3(mblocks, 2), 256, 0, stream>>>(h1, W2, h2pre, n, 256, 512, 256);
  agg1_kernel<4, true><<<n, 64, 0, stream>>>(h2pre, h2, rowptr, csr, ei, dis + (size_t)4 * n, b2, n);
  // layer 3: h3pre = h2 @ W3 [n,128]; agg+bias
  gemm_kernel<<<dim3(mblocks, 1), 256, 0, stream>>>(h2, W3, h3pre, n, 128, 256, 128);
  agg1_kernel<2, false><<<n, 64, 0, stream>>>(h3pre, h3, rowptr, csr, ei, dis + (size_t)4 * n, b3, n);

  pool_kernel<<<(n + 31) / 32, 128, 0, stream>>>(h3, batch, gsum, gmax, n);
  mlp_kernel<<<1, 512, 0, stream>>>(gsum, gmax, batch, n, Wm1, bm1, Wm2, bm2, out);
}

// Round 3
// 682.087 us; speedup vs baseline: 2.1069x; 1.3227x over previous
//
#include <hip/hip_runtime.h>

#define DEV_INLINE __device__ __forceinline__

typedef __attribute__((ext_vector_type(8))) short bf16x8;
typedef __attribute__((ext_vector_type(4))) float floatx4;

DEV_INLINE unsigned fencode(float f) {
  unsigned u = __float_as_uint(f);
  return (u & 0x80000000u) ? ~u : (u | 0x80000000u);
}
DEV_INLINE float fdecode(unsigned k) {
  return __uint_as_float((k & 0x80000000u) ? (k ^ 0x80000000u) : ~k);
}

DEV_INLINE unsigned short bf16_rne(float x) {
  unsigned u = __float_as_uint(x);
  unsigned r = (u + 0x7FFFu + ((u >> 16) & 1u)) >> 16;
  return (unsigned short)r;
}
DEV_INLINE void bf16_split(float x, unsigned short& hi, unsigned short& lo) {
  hi = bf16_rne(x);
  float hf = __uint_as_float(((unsigned)hi) << 16);
  lo = bf16_rne(x - hf);
}

#pragma clang diagnostic ignored "-Waddress-space-conversion"
DEV_INLINE void gload_lds16(const void* g, void* l) {
  __builtin_amdgcn_global_load_lds(
      (const __attribute__((address_space(1))) unsigned int*)g,
      (__attribute__((address_space(3))) unsigned int*)l, 16, 0, 0);
}

// ---------------- prep: transpose+split weights to bf16 hi/lo [N][K] planes ---
__global__ __launch_bounds__(256)
void prep_kernel(const float* __restrict__ WA, const float* __restrict__ WB,
                 const float* __restrict__ WC, const float* __restrict__ WD,
                 const float* __restrict__ bA, const float* __restrict__ bB,
                 const float* __restrict__ bC, const float* __restrict__ bD,
                 const float* __restrict__ W2, const float* __restrict__ W3,
                 unsigned short* __restrict__ W1t_hi, unsigned short* __restrict__ W1t_lo,
                 unsigned short* __restrict__ W2t_hi, unsigned short* __restrict__ W2t_lo,
                 unsigned short* __restrict__ W3t_hi, unsigned short* __restrict__ W3t_lo,
                 float* __restrict__ biascat) {
  int i = blockIdx.x * 256 + threadIdx.x;
  if (i < 65536) {  // W1 planes: [z][j out][k in]
    int z = i >> 14, rem = i & 16383, j = rem >> 7, k = rem & 127;
    const float* W = (z == 0) ? WA : (z == 1) ? WB : (z == 2) ? WC : WD;
    unsigned short hi, lo;
    bf16_split(W[k * 128 + j], hi, lo);
    W1t_hi[i] = hi; W1t_lo[i] = lo;
  } else if (i < 196608) {  // W2t [256][512]
    int i2 = i - 65536, j = i2 >> 9, k = i2 & 511;
    unsigned short hi, lo;
    bf16_split(W2[k * 256 + j], hi, lo);
    W2t_hi[i2] = hi; W2t_lo[i2] = lo;
  } else if (i < 229376) {  // W3t [128][256]
    int i3 = i - 196608, j = i3 >> 8, k = i3 & 255;
    unsigned short hi, lo;
    bf16_split(W3[k * 128 + j], hi, lo);
    W3t_hi[i3] = hi; W3t_lo[i3] = lo;
  } else if (i < 229888) {
    int i4 = i - 229376, c = i4 >> 7, j = i4 & 127;
    const float* b = (c == 0) ? bA : (c == 1) ? bB : (c == 2) ? bC : bD;
    biascat[i4] = b[j];
  }
}

// ---------------- in-degree histogram ----------------------------------------
__global__ __launch_bounds__(256)
void hist_kernel(const int* __restrict__ ei, int* __restrict__ cnt, int E) {
  int e = blockIdx.x * 256 + threadIdx.x;
  if (e < E) atomicAdd(&cnt[ei[E + e]], 1);
}

// ---------------- 3-level exclusive scan -------------------------------------
__global__ __launch_bounds__(256)
void scan1_kernel(const int* __restrict__ cnt, int* __restrict__ local,
                  int* __restrict__ bsum, int n) {
  __shared__ int s[256];
  int tid = threadIdx.x;
  int i = blockIdx.x * 256 + tid;
  int v = (i < n) ? cnt[i] : 0;
  s[tid] = v;
  __syncthreads();
#pragma unroll
  for (int off = 1; off < 256; off <<= 1) {
    int t = (tid >= off) ? s[tid - off] : 0;
    __syncthreads();
    s[tid] += t;
    __syncthreads();
  }
  if (i < n) local[i] = s[tid] - v;
  if (tid == 255) bsum[blockIdx.x] = s[255];
}

__global__ __launch_bounds__(256)
void scan2_kernel(int* __restrict__ bsum, int nb) {
  __shared__ int s[256];
  int tid = threadIdx.x;
  int v = (tid < nb) ? bsum[tid] : 0;
  s[tid] = v;
  __syncthreads();
#pragma unroll
  for (int off = 1; off < 256; off <<= 1) {
    int t = (tid >= off) ? s[tid - off] : 0;
    __syncthreads();
    s[tid] += t;
    __syncthreads();
  }
  if (tid < nb) bsum[tid] = s[tid] - v;  // exclusive
}

__global__ __launch_bounds__(256)
void scan3_kernel(const int* __restrict__ local, const int* __restrict__ bsum,
                  int* __restrict__ rowptr, int* __restrict__ rowwork, int n, int E) {
  int i = blockIdx.x * 256 + threadIdx.x;
  if (i < n) {
    int rp = local[i] + bsum[blockIdx.x];
    rowptr[i] = rp;
    rowwork[i] = rp;
  }
  if (i == 0) rowptr[n] = E;
}

// ---------------- CSR fill ----------------------------------------------------
__global__ __launch_bounds__(256)
void fill_kernel(const int* __restrict__ ei, int* __restrict__ rowwork,
                 int* __restrict__ csr, int E) {
  int e = blockIdx.x * 256 + threadIdx.x;
  if (e >= E) return;
  int d = ei[E + e];
  int pos = atomicAdd(&rowwork[d], 1);
  csr[pos] = e;
}

// ---------------- degrees from CSR (node-centric, fused rsqrt) ----------------
__global__ __launch_bounds__(256)
void degcsr_kernel(const int* __restrict__ rowptr, const int* __restrict__ csr,
                   const float* __restrict__ eattr, float* __restrict__ dis, int n) {
  int d = blockIdx.x * 256 + threadIdx.x;
  if (d >= n) return;
  int beg = rowptr[d], end = rowptr[d + 1];
  float s0 = 1.f, s1 = 1.f, s2 = 1.f, s3 = 1.f;  // self-loop weight 1
  for (int i = beg; i < end; ++i) {
    int e = csr[i];
    float4 w = ((const float4*)eattr)[e];
    s0 += w.x; s1 += w.y; s2 += w.z; s3 += w.w;
  }
  dis[d]         = 1.0f / sqrtf(s0);
  dis[n + d]     = 1.0f / sqrtf(s1);
  dis[2 * n + d] = 1.0f / sqrtf(s2);
  dis[3 * n + d] = 1.0f / sqrtf(s3);
  dis[4 * n + d] = 1.0f / sqrtf(1.0f + (float)(end - beg));
}

// ---------------- layer-1 aggregation on raw x; bf16 hi/lo split output -------
__global__ __launch_bounds__(64)
void agg4x_kernel(const float* __restrict__ x,
                  unsigned short* __restrict__ xa_hi, unsigned short* __restrict__ xa_lo,
                  const int* __restrict__ rowptr, const int* __restrict__ csr,
                  const int* __restrict__ ei, const float* __restrict__ eattr,
                  const float* __restrict__ dis, int n, int npad) {
  int d = blockIdx.x;
  int t = threadIdx.x;
  float dc0 = dis[d], dc1 = dis[n + d], dc2 = dis[2 * n + d], dc3 = dis[3 * n + d];
  const float2* x2 = (const float2*)x;
  float2 xv = x2[(size_t)d * 64 + t];
  float a0x = xv.x * dc0 * dc0, a0y = xv.y * dc0 * dc0;
  float a1x = xv.x * dc1 * dc1, a1y = xv.y * dc1 * dc1;
  float a2x = xv.x * dc2 * dc2, a2y = xv.y * dc2 * dc2;
  float a3x = xv.x * dc3 * dc3, a3y = xv.y * dc3 * dc3;
  int beg = rowptr[d], end = rowptr[d + 1];
  for (int i = beg; i < end; ++i) {
    int e = csr[i];
    int s = ei[e];
    float4 w = ((const float4*)eattr)[e];
    float n0 = dis[s] * w.x * dc0;
    float n1 = dis[n + s] * w.y * dc1;
    float n2 = dis[2 * n + s] * w.z * dc2;
    float n3 = dis[3 * n + s] * w.w * dc3;
    float2 h = x2[(size_t)s * 64 + t];
    a0x += h.x * n0; a0y += h.y * n0;
    a1x += h.x * n1; a1y += h.y * n1;
    a2x += h.x * n2; a2y += h.y * n2;
    a3x += h.x * n3; a3y += h.y * n3;
  }
  size_t plane = (size_t)npad * 128;
  size_t base = (size_t)d * 128 + 2 * t;
  float vx[4] = {a0x, a1x, a2x, a3x};
  float vy[4] = {a0y, a1y, a2y, a3y};
#pragma unroll
  for (int z = 0; z < 4; ++z) {
    unsigned short hx, lx, hy, ly;
    bf16_split(vx[z], hx, lx);
    bf16_split(vy[z], hy, ly);
    ushort2 h2v; h2v.x = hx; h2v.y = hy;
    ushort2 l2v; l2v.x = lx; l2v.y = ly;
    *(ushort2*)&xa_hi[plane * z + base] = h2v;
    *(ushort2*)&xa_lo[plane * z + base] = l2v;
  }
}

// ---------------- MFMA split-bf16 GEMM body -----------------------------------
// C[128x128 tile] = A @ B^T via 3 MFMAs (hi*hi + hi*lo + lo*hi), fp32 acc.
// A planes [*][K] bf16 row-major; Bt planes [N][K] bf16. 256 thr = 4 waves,
// each wave one 64x64 quadrant (4x4 frags of 16x16x32).
template <bool OUTSPLIT>
DEV_INLINE void gemm_mfma_body(const unsigned short* __restrict__ Ah,
                               const unsigned short* __restrict__ Al, int K,
                               const unsigned short* __restrict__ Bh,
                               const unsigned short* __restrict__ Bl, int nTile0,
                               float* __restrict__ C, int ldc, int col0,
                               unsigned short* __restrict__ Chi,
                               unsigned short* __restrict__ Clo,
                               const float* __restrict__ bias, int M, int row0) {
  __shared__ __align__(16) unsigned short As[2][128 * 32];
  __shared__ __align__(16) unsigned short Bs[2][128 * 32];
  int tid = threadIdx.x;
  int w = tid >> 6, lane = tid & 63;
  int quad = lane >> 4, lrow = lane & 15;
  int wm = (w >> 1) * 64, wn = (w & 1) * 64;
  int srow = lane >> 2;         // 0..15 (staging row within 16-row chunk)
  int scol8 = (lane & 3) * 8;   // ushort offset within 32-k row

  floatx4 zero4 = {0.f, 0.f, 0.f, 0.f};
  floatx4 acc[4][4];
#pragma unroll
  for (int i = 0; i < 4; ++i)
#pragma unroll
    for (int j = 0; j < 4; ++j) acc[i][j] = zero4;

  for (int k0 = 0; k0 < K; k0 += 32) {
#pragma unroll
    for (int q = 0; q < 2; ++q) {
      int r = w * 32 + q * 16 + srow;
      size_t ga = (size_t)(row0 + r) * K + k0 + scol8;
      size_t gb = (size_t)(nTile0 + r) * K + k0 + scol8;
      int lo = (w * 32 + q * 16) * 32;
      gload_lds16(Ah + ga, &As[0][lo]);
      gload_lds16(Al + ga, &As[1][lo]);
      gload_lds16(Bh + gb, &Bs[0][lo]);
      gload_lds16(Bl + gb, &Bs[1][lo]);
    }
    __syncthreads();  // drains vmcnt(0) + barrier
    bf16x8 ah[4], al[4];
#pragma unroll
    for (int i = 0; i < 4; ++i) {
      int off = (wm + i * 16 + lrow) * 32 + quad * 8;
      ah[i] = *(const bf16x8*)&As[0][off];
      al[i] = *(const bf16x8*)&As[1][off];
    }
#pragma unroll
    for (int j = 0; j < 4; ++j) {
      int off = (wn + j * 16 + lrow) * 32 + quad * 8;
      bf16x8 bh = *(const bf16x8*)&Bs[0][off];
      bf16x8 bl = *(const bf16x8*)&Bs[1][off];
#pragma unroll
      for (int i = 0; i < 4; ++i) {
        acc[i][j] = __builtin_amdgcn_mfma_f32_16x16x32_bf16(ah[i], bh, acc[i][j], 0, 0, 0);
        acc[i][j] = __builtin_amdgcn_mfma_f32_16x16x32_bf16(ah[i], bl, acc[i][j], 0, 0, 0);
        acc[i][j] = __builtin_amdgcn_mfma_f32_16x16x32_bf16(al[i], bh, acc[i][j], 0, 0, 0);
      }
    }
    __syncthreads();
  }
  // epilogue: C/D layout col=lane&15, row=quad*4+reg
#pragma unroll
  for (int i = 0; i < 4; ++i) {
#pragma unroll
    for (int j = 0; j < 4; ++j) {
      int colL = wn + j * 16 + lrow;
#pragma unroll
      for (int r = 0; r < 4; ++r) {
        int row = row0 + wm + i * 16 + quad * 4 + r;
        if (row < M) {
          float v = acc[i][j][r];
          if (OUTSPLIT) {
            v = fmaxf(v + bias[colL], 0.0f);
            unsigned short hi, lo;
            bf16_split(v, hi, lo);
            Chi[(size_t)row * ldc + col0 + colL] = hi;
            Clo[(size_t)row * ldc + col0 + colL] = lo;
          } else {
            C[(size_t)row * ldc + col0 + colL] = v;
          }
        }
      }
    }
  }
}

// layer-1: z-batched, bias+relu, split-bf16 out into h1 planes [npad][512]
__global__ __launch_bounds__(256)
void gemm_l1_mfma(const unsigned short* __restrict__ xa_hi,
                  const unsigned short* __restrict__ xa_lo,
                  const unsigned short* __restrict__ W1t_hi,
                  const unsigned short* __restrict__ W1t_lo,
                  const float* __restrict__ biascat,
                  unsigned short* __restrict__ h1_hi, unsigned short* __restrict__ h1_lo,
                  int M, int npad) {
  int z = blockIdx.z;
  size_t ap = (size_t)z * npad * 128;
  gemm_mfma_body<true>(xa_hi + ap, xa_lo + ap, 128,
                       W1t_hi + z * 16384, W1t_lo + z * 16384, 0,
                       nullptr, 512, z * 128, h1_hi, h1_lo,
                       biascat + z * 128, M, blockIdx.x * 128);
}

// generic fp32-out GEMM (layers 2 and 3)
__global__ __launch_bounds__(256)
void gemm_f32out(const unsigned short* __restrict__ Ah, const unsigned short* __restrict__ Al,
                 int K, const unsigned short* __restrict__ Bh,
                 const unsigned short* __restrict__ Bl, float* __restrict__ C, int ldc,
                 int M) {
  gemm_mfma_body<false>(Ah, Al, K, Bh, Bl, blockIdx.y * 128,
                        C, ldc, blockIdx.y * 128, nullptr, nullptr, nullptr, M,
                        blockIdx.x * 128);
}

// ---------------- layers 2/3 aggregation (edge weight = 1) --------------------
template <int VEC, bool RELU, bool OUTSPLIT>
__global__ __launch_bounds__(64)
void agg1_kernel(const float* __restrict__ hin, float* __restrict__ out,
                 unsigned short* __restrict__ ohi, unsigned short* __restrict__ olo,
                 const int* __restrict__ rowptr, const int* __restrict__ csr,
                 const int* __restrict__ ei, const float* __restrict__ dis1,
                 const float* __restrict__ bias, int n) {
  constexpr int DOUT = VEC * 64;
  int d = blockIdx.x;
  int t = threadIdx.x;
  float dd = dis1[d];
  float acc[VEC];
  {
    float sw = dd * dd;
#pragma unroll
    for (int k = 0; k < VEC; ++k) acc[k] = hin[(size_t)d * DOUT + t * VEC + k] * sw;
  }
  int beg = rowptr[d], end = rowptr[d + 1];
  for (int i = beg; i < end; ++i) {
    int e = csr[i];
    int s = ei[e];
    float nrm = dis1[s] * dd;
    if (VEC == 4) {
      float4 h = *(const float4*)&hin[(size_t)s * DOUT + t * 4];
      acc[0] += h.x * nrm; acc[1] += h.y * nrm;
      acc[2 % VEC] += h.z * nrm; acc[3 % VEC] += h.w * nrm;
    } else {
      float2 h = *(const float2*)&hin[(size_t)s * DOUT + t * 2];
      acc[0] += h.x * nrm; acc[1 % VEC] += h.y * nrm;
    }
  }
#pragma unroll
  for (int k = 0; k < VEC; ++k) {
    float r = acc[k] + bias[t * VEC + k];
    if (RELU) r = fmaxf(r, 0.0f);
    if (OUTSPLIT) {
      unsigned short hi, lo;
      bf16_split(r, hi, lo);
      ohi[(size_t)d * DOUT + t * VEC + k] = hi;
      olo[(size_t)d * DOUT + t * VEC + k] = lo;
    } else {
      out[(size_t)d * DOUT + t * VEC + k] = r;
    }
  }
}

// ---------------- pooling: per-graph sum + max (encoded uint) -----------------
__global__ __launch_bounds__(128)
void pool_kernel(const float* __restrict__ h3, const int* __restrict__ batch,
                 float* __restrict__ gsum, unsigned* __restrict__ gmax, int n) {
  int c = threadIdx.x;
  int start = blockIdx.x * 32;
  int end = min(start + 32, n);
  int curg = -1;
  float s = 0.0f, m = -3.402823466e38f;
  for (int i = start; i < end; ++i) {
    int g = batch[i];  // sorted; wave-uniform
    if (g != curg) {
      if (curg >= 0) {
        atomicAdd(&gsum[curg * 128 + c], s);
        atomicMax(&gmax[curg * 128 + c], fencode(m));
      }
      curg = g; s = 0.0f; m = -3.402823466e38f;
    }
    float v = h3[(size_t)i * 128 + c];
    s += v;
    m = fmaxf(m, v);
  }
  if (curg >= 0) {
    atomicAdd(&gsum[curg * 128 + c], s);
    atomicMax(&gmax[curg * 128 + c], fencode(m));
  }
}

// ---------------- final MLP; per-graph counts via binary search ---------------
__global__ __launch_bounds__(512)
void mlp_kernel(const float* __restrict__ gsum, const unsigned* __restrict__ gmax,
                const int* __restrict__ batch, int n, const float* __restrict__ Wm1,
                const float* __restrict__ bm1, const float* __restrict__ Wm2,
                const float* __restrict__ bm2, float* __restrict__ out) {
  __shared__ float hid[64][8];
  int t = threadIdx.x;
  int gi = t >> 3, u = t & 7;
  auto lb = [&](int key) {
    int lo = 0, hi = n;
    while (lo < hi) {
      int mid = (lo + hi) >> 1;
      if (batch[mid] < key) lo = mid + 1; else hi = mid;
    }
    return lo;
  };
  int cnt = lb(gi + 1) - lb(gi);
  float inv = 1.0f / fmaxf((float)cnt, 1.0f);
  float s = bm1[u];
  for (int k = 0; k < 128; ++k) {
    float mean = gsum[gi * 128 + k] * inv;
    s += mean * Wm1[k * 8 + u];
  }
  for (int k = 0; k < 128; ++k) {
    float mx = (cnt > 0) ? fdecode(gmax[gi * 128 + k]) : 0.0f;
    s += mx * Wm1[(128 + k) * 8 + u];
  }
  hid[gi][u] = fmaxf(s, 0.0f);
  __syncthreads();
  if (t < 128) {
    int g2 = t >> 1, o = t & 1;
    float s2 = bm2[o];
#pragma unroll
    for (int uu = 0; uu < 8; ++uu) s2 += hid[g2][uu] * Wm2[uu * 2 + o];
    out[g2 * 2 + o] = s2;
  }
}

extern "C" void kernel_launch(void* const* d_in, const int* in_sizes, int n_in,
                              void* d_out, int out_size, void* d_ws, size_t ws_size,
                              hipStream_t stream) {
  const float* x     = (const float*)d_in[0];
  const int*   ei    = (const int*)d_in[1];
  const float* eattr = (const float*)d_in[2];
  const int*   batch = (const int*)d_in[3];
  const float* W1A = (const float*)d_in[4],  *b1A = (const float*)d_in[5];
  const float* W1B = (const float*)d_in[6],  *b1B = (const float*)d_in[7];
  const float* W1C = (const float*)d_in[8],  *b1C = (const float*)d_in[9];
  const float* W1D = (const float*)d_in[10], *b1D = (const float*)d_in[11];
  const float* W2  = (const float*)d_in[12], *b2  = (const float*)d_in[13];
  const float* W3  = (const float*)d_in[14], *b3  = (const float*)d_in[15];
  const float* Wm1 = (const float*)d_in[16], *bm1 = (const float*)d_in[17];
  const float* Wm2 = (const float*)d_in[18], *bm2 = (const float*)d_in[19];
  float* out = (float*)d_out;

  const int n = in_sizes[0] / 128;
  const int E = in_sizes[1] / 2;
  const int npad = (n + 127) & ~127;
  const int nmb = npad / 128;

  char* ws = (char*)d_ws;
  size_t off = 0;
  auto alloc = [&](size_t bytes) -> void* {
    void* p = ws + off;
    off += (bytes + 255) & ~(size_t)255;
    return p;
  };

  float*    dis     = (float*)alloc((size_t)5 * n * 4);
  int*      rowptr  = (int*)alloc(((size_t)n + 1) * 4);
  int*      rowwork = (int*)alloc((size_t)n * 4);
  int*      local   = (int*)alloc((size_t)n * 4);
  int*      bsum    = (int*)alloc(256 * 4);
  // ---- zero block start ----
  size_t zoff = off;
  int*      cnt     = (int*)alloc((size_t)n * 4);
  float*    gsum    = (float*)alloc(64 * 128 * 4);
  unsigned* gmax    = (unsigned*)alloc(64 * 128 * 4);
  size_t zbytes = off - zoff;
  // ---- zero block end ----
  int*      csr     = (int*)alloc((size_t)E * 4);
  unsigned short* W1t_hi = (unsigned short*)alloc(65536 * 2);
  unsigned short* W1t_lo = (unsigned short*)alloc(65536 * 2);
  unsigned short* W2t_hi = (unsigned short*)alloc(131072 * 2);
  unsigned short* W2t_lo = (unsigned short*)alloc(131072 * 2);
  unsigned short* W3t_hi = (unsigned short*)alloc(32768 * 2);
  unsigned short* W3t_lo = (unsigned short*)alloc(32768 * 2);
  float*    biascat = (float*)alloc(512 * 4);
  unsigned short* xa_hi = (unsigned short*)alloc((size_t)4 * npad * 128 * 2);
  unsigned short* xa_lo = (unsigned short*)alloc((size_t)4 * npad * 128 * 2);
  unsigned short* h1_hi = (unsigned short*)alloc((size_t)npad * 512 * 2);
  unsigned short* h1_lo = (unsigned short*)alloc((size_t)npad * 512 * 2);

  // lifetime-safe reuse:
  float* h2pre = (float*)xa_hi;                 // [npad,256] fp32 (xa dead after gemm_l1)
  float* h3pre = (float*)xa_lo;                 // [npad,128] fp32 (dead after agg1<4>... written by gemm_l3)
  unsigned short* h2_hi = h1_hi;                // [npad,256] (h1 dead after gemm_l2)
  unsigned short* h2_lo = h1_hi + (size_t)npad * 256;
  float* h3 = (float*)h1_lo;                    // [npad,128] fp32 (h1_lo dead after gemm_l2)

  hipMemsetAsync(ws + zoff, 0, zbytes, stream);

  prep_kernel<<<(229888 + 255) / 256, 256, 0, stream>>>(
      W1A, W1B, W1C, W1D, b1A, b1B, b1C, b1D, W2, W3,
      W1t_hi, W1t_lo, W2t_hi, W2t_lo, W3t_hi, W3t_lo, biascat);

  int nb = (n + 255) / 256;
  hist_kernel<<<(E + 255) / 256, 256, 0, stream>>>(ei, cnt, E);
  scan1_kernel<<<nb, 256, 0, stream>>>(cnt, local, bsum, n);
  scan2_kernel<<<1, 256, 0, stream>>>(bsum, nb);
  scan3_kernel<<<nb, 256, 0, stream>>>(local, bsum, rowptr, rowwork, n, E);
  fill_kernel<<<(E + 255) / 256, 256, 0, stream>>>(ei, rowwork, csr, E);
  degcsr_kernel<<<(n + 255) / 256, 256, 0, stream>>>(rowptr, csr, eattr, dis, n);

  // layer 1: aggregate x (4 norms) -> split-bf16 planes; 4 batched MFMA GEMMs
  agg4x_kernel<<<n, 64, 0, stream>>>(x, xa_hi, xa_lo, rowptr, csr, ei, eattr, dis, n, npad);
  gemm_l1_mfma<<<dim3(nmb, 1, 4), 256, 0, stream>>>(xa_hi, xa_lo, W1t_hi, W1t_lo,
                                                    biascat, h1_hi, h1_lo, n, npad);
  // layer 2: h2pre = h1 @ W2 [n,256] fp32; agg+bias+relu -> split-bf16 h2
  gemm_f32out<<<dim3(nmb, 2), 256, 0, stream>>>(h1_hi, h1_lo, 512, W2t_hi, W2t_lo,
                                                h2pre, 256, n);
  agg1_kernel<4, true, true><<<n, 64, 0, stream>>>(h2pre, nullptr, h2_hi, h2_lo,
                                                   rowptr, csr, ei, dis + (size_t)4 * n, b2, n);
  // layer 3: h3pre = h2 @ W3 [n,128] fp32; agg+bias -> fp32 h3
  gemm_f32out<<<dim3(nmb, 1), 256, 0, stream>>>(h2_hi, h2_lo, 256, W3t_hi, W3t_lo,
                                                h3pre, 128, n);
  agg1_kernel<2, false, false><<<n, 64, 0, stream>>>(h3pre, h3, nullptr, nullptr,
                                                     rowptr, csr, ei, dis + (size_t)4 * n, b3, n);

  pool_kernel<<<(n + 31) / 32, 128, 0, stream>>>(h3, batch, gsum, gmax, n);
  mlp_kernel<<<1, 512, 0, stream>>>(gsum, gmax, batch, n, Wm1, bm1, Wm2, bm2, out);
}

// Round 4
// 631.140 us; speedup vs baseline: 2.2770x; 1.0807x over previous
//
#include <hip/hip_runtime.h>

#define DEV_INLINE __device__ __forceinline__

typedef __attribute__((ext_vector_type(8))) short bf16x8;
typedef __attribute__((ext_vector_type(4))) float floatx4;

DEV_INLINE unsigned fencode(float f) {
  unsigned u = __float_as_uint(f);
  return (u & 0x80000000u) ? ~u : (u | 0x80000000u);
}
DEV_INLINE float fdecode(unsigned k) {
  return __uint_as_float((k & 0x80000000u) ? (k ^ 0x80000000u) : ~k);
}

DEV_INLINE unsigned short bf16_rne(float x) {
  unsigned u = __float_as_uint(x);
  unsigned r = (u + 0x7FFFu + ((u >> 16) & 1u)) >> 16;
  return (unsigned short)r;
}
DEV_INLINE void bf16_split(float x, unsigned short& hi, unsigned short& lo) {
  hi = bf16_rne(x);
  float hf = __uint_as_float(((unsigned)hi) << 16);
  lo = bf16_rne(x - hf);
}

#pragma clang diagnostic ignored "-Waddress-space-conversion"
DEV_INLINE void gload_lds16(const void* g, void* l) {
  __builtin_amdgcn_global_load_lds(
      (const __attribute__((address_space(1))) unsigned int*)g,
      (__attribute__((address_space(3))) unsigned int*)l, 16, 0, 0);
}

// ---------------- prep: transpose+split weights to bf16 hi/lo [N][K] planes ---
__global__ __launch_bounds__(256)
void prep_kernel(const float* __restrict__ WA, const float* __restrict__ WB,
                 const float* __restrict__ WC, const float* __restrict__ WD,
                 const float* __restrict__ bA, const float* __restrict__ bB,
                 const float* __restrict__ bC, const float* __restrict__ bD,
                 const float* __restrict__ W2, const float* __restrict__ W3,
                 unsigned short* __restrict__ W1t_hi, unsigned short* __restrict__ W1t_lo,
                 unsigned short* __restrict__ W2t_hi, unsigned short* __restrict__ W2t_lo,
                 unsigned short* __restrict__ W3t_hi, unsigned short* __restrict__ W3t_lo,
                 float* __restrict__ biascat) {
  int i = blockIdx.x * 256 + threadIdx.x;
  if (i < 65536) {  // W1 planes: [z][j out][k in]
    int z = i >> 14, rem = i & 16383, j = rem >> 7, k = rem & 127;
    const float* W = (z == 0) ? WA : (z == 1) ? WB : (z == 2) ? WC : WD;
    unsigned short hi, lo;
    bf16_split(W[k * 128 + j], hi, lo);
    W1t_hi[i] = hi; W1t_lo[i] = lo;
  } else if (i < 196608) {  // W2t [256][512]
    int i2 = i - 65536, j = i2 >> 9, k = i2 & 511;
    unsigned short hi, lo;
    bf16_split(W2[k * 256 + j], hi, lo);
    W2t_hi[i2] = hi; W2t_lo[i2] = lo;
  } else if (i < 229376) {  // W3t [128][256]
    int i3 = i - 196608, j = i3 >> 8, k = i3 & 255;
    unsigned short hi, lo;
    bf16_split(W3[k * 128 + j], hi, lo);
    W3t_hi[i3] = hi; W3t_lo[i3] = lo;
  } else if (i < 229888) {
    int i4 = i - 229376, c = i4 >> 7, j = i4 & 127;
    const float* b = (c == 0) ? bA : (c == 1) ? bB : (c == 2) ? bC : bD;
    biascat[i4] = b[j];
  }
}

// ---------------- in-degree histogram ----------------------------------------
__global__ __launch_bounds__(256)
void hist_kernel(const int* __restrict__ ei, int* __restrict__ cnt, int E) {
  int e = blockIdx.x * 256 + threadIdx.x;
  if (e < E) atomicAdd(&cnt[ei[E + e]], 1);
}

// ---------------- 3-level exclusive scan -------------------------------------
__global__ __launch_bounds__(256)
void scan1_kernel(const int* __restrict__ cnt, int* __restrict__ local,
                  int* __restrict__ bsum, int n) {
  __shared__ int s[256];
  int tid = threadIdx.x;
  int i = blockIdx.x * 256 + tid;
  int v = (i < n) ? cnt[i] : 0;
  s[tid] = v;
  __syncthreads();
#pragma unroll
  for (int off = 1; off < 256; off <<= 1) {
    int t = (tid >= off) ? s[tid - off] : 0;
    __syncthreads();
    s[tid] += t;
    __syncthreads();
  }
  if (i < n) local[i] = s[tid] - v;
  if (tid == 255) bsum[blockIdx.x] = s[255];
}

__global__ __launch_bounds__(256)
void scan2_kernel(int* __restrict__ bsum, int nb) {
  __shared__ int s[256];
  int tid = threadIdx.x;
  int v = (tid < nb) ? bsum[tid] : 0;
  s[tid] = v;
  __syncthreads();
#pragma unroll
  for (int off = 1; off < 256; off <<= 1) {
    int t = (tid >= off) ? s[tid - off] : 0;
    __syncthreads();
    s[tid] += t;
    __syncthreads();
  }
  if (tid < nb) bsum[tid] = s[tid] - v;  // exclusive
}

__global__ __launch_bounds__(256)
void scan3_kernel(const int* __restrict__ local, const int* __restrict__ bsum,
                  int* __restrict__ rowptr, int* __restrict__ rowwork, int n, int E) {
  int i = blockIdx.x * 256 + threadIdx.x;
  if (i < n) {
    int rp = local[i] + bsum[blockIdx.x];
    rowptr[i] = rp;
    rowwork[i] = rp;
  }
  if (i == 0) rowptr[n] = E;
}

// ---------------- CSR fill (also writes src/dst per slot) ---------------------
__global__ __launch_bounds__(256)
void fill_kernel(const int* __restrict__ ei, int* __restrict__ rowwork,
                 int* __restrict__ csr, int* __restrict__ csr_src,
                 int* __restrict__ csr_dst, int E) {
  int e = blockIdx.x * 256 + threadIdx.x;
  if (e >= E) return;
  int d = ei[E + e];
  int pos = atomicAdd(&rowwork[d], 1);
  csr[pos] = e;
  csr_src[pos] = ei[e];
  csr_dst[pos] = d;
}

// ---------------- degrees from CSR (node-centric, fused rsqrt) ----------------
__global__ __launch_bounds__(256)
void degcsr_kernel(const int* __restrict__ rowptr, const int* __restrict__ csr,
                   const float* __restrict__ eattr, float* __restrict__ dis, int n) {
  int d = blockIdx.x * 256 + threadIdx.x;
  if (d >= n) return;
  int beg = rowptr[d], end = rowptr[d + 1];
  float s0 = 1.f, s1 = 1.f, s2 = 1.f, s3 = 1.f;  // self-loop weight 1
  for (int i = beg; i < end; ++i) {
    int e = csr[i];
    float4 w = ((const float4*)eattr)[e];
    s0 += w.x; s1 += w.y; s2 += w.z; s3 += w.w;
  }
  dis[d]         = 1.0f / sqrtf(s0);
  dis[n + d]     = 1.0f / sqrtf(s1);
  dis[2 * n + d] = 1.0f / sqrtf(s2);
  dis[3 * n + d] = 1.0f / sqrtf(s3);
  dis[4 * n + d] = 1.0f / sqrtf(1.0f + (float)(end - beg));
}

// ---------------- per-CSR-slot norms (edge-parallel, breaks dep chains) -------
__global__ __launch_bounds__(256)
void edgeprep_kernel(const int* __restrict__ csr, const int* __restrict__ csr_src,
                     const int* __restrict__ csr_dst, const float* __restrict__ eattr,
                     const float* __restrict__ dis, float4* __restrict__ norm4,
                     float* __restrict__ norm1, int n, int E) {
  int i = blockIdx.x * 256 + threadIdx.x;
  if (i >= E) return;
  int e = csr[i], s = csr_src[i], d = csr_dst[i];
  float4 w = ((const float4*)eattr)[e];
  float4 o;
  o.x = dis[s] * w.x * dis[d];
  o.y = dis[n + s] * w.y * dis[n + d];
  o.z = dis[2 * n + s] * w.z * dis[2 * n + d];
  o.w = dis[3 * n + s] * w.w * dis[3 * n + d];
  norm4[i] = o;
  norm1[i] = dis[4 * n + s] * dis[4 * n + d];
}

// ---------------- layer-1 aggregation on raw x; bf16 hi/lo split output -------
// one block (64 thr) per node; 4-edge unrolled for MLP
__global__ __launch_bounds__(64)
void agg4x_kernel(const float* __restrict__ x,
                  unsigned short* __restrict__ xa_hi, unsigned short* __restrict__ xa_lo,
                  const int* __restrict__ rowptr, const int* __restrict__ csr_src,
                  const float4* __restrict__ norm4, const float* __restrict__ dis,
                  int n, int npad) {
  int d = blockIdx.x;
  int t = threadIdx.x;
  float dc0 = dis[d], dc1 = dis[n + d], dc2 = dis[2 * n + d], dc3 = dis[3 * n + d];
  const float2* x2 = (const float2*)x;
  float2 xv = x2[(size_t)d * 64 + t];
  float a0x = xv.x * dc0 * dc0, a0y = xv.y * dc0 * dc0;
  float a1x = xv.x * dc1 * dc1, a1y = xv.y * dc1 * dc1;
  float a2x = xv.x * dc2 * dc2, a2y = xv.y * dc2 * dc2;
  float a3x = xv.x * dc3 * dc3, a3y = xv.y * dc3 * dc3;
  int beg = rowptr[d], end = rowptr[d + 1];
  int i = beg;
  for (; i + 4 <= end; i += 4) {
    int s0 = csr_src[i], s1 = csr_src[i + 1], s2 = csr_src[i + 2], s3 = csr_src[i + 3];
    float4 m0 = norm4[i], m1 = norm4[i + 1], m2 = norm4[i + 2], m3 = norm4[i + 3];
    float2 h0 = x2[(size_t)s0 * 64 + t];
    float2 h1 = x2[(size_t)s1 * 64 + t];
    float2 h2 = x2[(size_t)s2 * 64 + t];
    float2 h3 = x2[(size_t)s3 * 64 + t];
    a0x += h0.x * m0.x; a0y += h0.y * m0.x;
    a1x += h0.x * m0.y; a1y += h0.y * m0.y;
    a2x += h0.x * m0.z; a2y += h0.y * m0.z;
    a3x += h0.x * m0.w; a3y += h0.y * m0.w;
    a0x += h1.x * m1.x; a0y += h1.y * m1.x;
    a1x += h1.x * m1.y; a1y += h1.y * m1.y;
    a2x += h1.x * m1.z; a2y += h1.y * m1.z;
    a3x += h1.x * m1.w; a3y += h1.y * m1.w;
    a0x += h2.x * m2.x; a0y += h2.y * m2.x;
    a1x += h2.x * m2.y; a1y += h2.y * m2.y;
    a2x += h2.x * m2.z; a2y += h2.y * m2.z;
    a3x += h2.x * m2.w; a3y += h2.y * m2.w;
    a0x += h3.x * m3.x; a0y += h3.y * m3.x;
    a1x += h3.x * m3.y; a1y += h3.y * m3.y;
    a2x += h3.x * m3.z; a2y += h3.y * m3.z;
    a3x += h3.x * m3.w; a3y += h3.y * m3.w;
  }
  for (; i < end; ++i) {
    int s = csr_src[i];
    float4 m = norm4[i];
    float2 h = x2[(size_t)s * 64 + t];
    a0x += h.x * m.x; a0y += h.y * m.x;
    a1x += h.x * m.y; a1y += h.y * m.y;
    a2x += h.x * m.z; a2y += h.y * m.z;
    a3x += h.x * m.w; a3y += h.y * m.w;
  }
  size_t plane = (size_t)npad * 128;
  size_t base = (size_t)d * 128 + 2 * t;
  float vx[4] = {a0x, a1x, a2x, a3x};
  float vy[4] = {a0y, a1y, a2y, a3y};
#pragma unroll
  for (int z = 0; z < 4; ++z) {
    unsigned short hx, lx, hy, ly;
    bf16_split(vx[z], hx, lx);
    bf16_split(vy[z], hy, ly);
    ushort2 h2v; h2v.x = hx; h2v.y = hy;
    ushort2 l2v; l2v.x = lx; l2v.y = ly;
    *(ushort2*)&xa_hi[plane * z + base] = h2v;
    *(ushort2*)&xa_lo[plane * z + base] = l2v;
  }
}

// ---------------- MFMA split-bf16 GEMM body -----------------------------------
template <bool OUTSPLIT>
DEV_INLINE void gemm_mfma_body(const unsigned short* __restrict__ Ah,
                               const unsigned short* __restrict__ Al, int K,
                               const unsigned short* __restrict__ Bh,
                               const unsigned short* __restrict__ Bl, int nTile0,
                               float* __restrict__ C, int ldc, int col0,
                               unsigned short* __restrict__ Chi,
                               unsigned short* __restrict__ Clo,
                               const float* __restrict__ bias, int M, int row0) {
  __shared__ __align__(16) unsigned short As[2][128 * 32];
  __shared__ __align__(16) unsigned short Bs[2][128 * 32];
  int tid = threadIdx.x;
  int w = tid >> 6, lane = tid & 63;
  int quad = lane >> 4, lrow = lane & 15;
  int wm = (w >> 1) * 64, wn = (w & 1) * 64;
  int srow = lane >> 2;
  int scol8 = (lane & 3) * 8;

  floatx4 zero4 = {0.f, 0.f, 0.f, 0.f};
  floatx4 acc[4][4];
#pragma unroll
  for (int i = 0; i < 4; ++i)
#pragma unroll
    for (int j = 0; j < 4; ++j) acc[i][j] = zero4;

  for (int k0 = 0; k0 < K; k0 += 32) {
#pragma unroll
    for (int q = 0; q < 2; ++q) {
      int r = w * 32 + q * 16 + srow;
      size_t ga = (size_t)(row0 + r) * K + k0 + scol8;
      size_t gb = (size_t)(nTile0 + r) * K + k0 + scol8;
      int lo = (w * 32 + q * 16) * 32;
      gload_lds16(Ah + ga, &As[0][lo]);
      gload_lds16(Al + ga, &As[1][lo]);
      gload_lds16(Bh + gb, &Bs[0][lo]);
      gload_lds16(Bl + gb, &Bs[1][lo]);
    }
    __syncthreads();
    bf16x8 ah[4], al[4];
#pragma unroll
    for (int i = 0; i < 4; ++i) {
      int off = (wm + i * 16 + lrow) * 32 + quad * 8;
      ah[i] = *(const bf16x8*)&As[0][off];
      al[i] = *(const bf16x8*)&As[1][off];
    }
#pragma unroll
    for (int j = 0; j < 4; ++j) {
      int off = (wn + j * 16 + lrow) * 32 + quad * 8;
      bf16x8 bh = *(const bf16x8*)&Bs[0][off];
      bf16x8 bl = *(const bf16x8*)&Bs[1][off];
#pragma unroll
      for (int i = 0; i < 4; ++i) {
        acc[i][j] = __builtin_amdgcn_mfma_f32_16x16x32_bf16(ah[i], bh, acc[i][j], 0, 0, 0);
        acc[i][j] = __builtin_amdgcn_mfma_f32_16x16x32_bf16(ah[i], bl, acc[i][j], 0, 0, 0);
        acc[i][j] = __builtin_amdgcn_mfma_f32_16x16x32_bf16(al[i], bh, acc[i][j], 0, 0, 0);
      }
    }
    __syncthreads();
  }
#pragma unroll
  for (int i = 0; i < 4; ++i) {
#pragma unroll
    for (int j = 0; j < 4; ++j) {
      int colL = wn + j * 16 + lrow;
#pragma unroll
      for (int r = 0; r < 4; ++r) {
        int row = row0 + wm + i * 16 + quad * 4 + r;
        if (row < M) {
          float v = acc[i][j][r];
          if (OUTSPLIT) {
            v = fmaxf(v + bias[colL], 0.0f);
            unsigned short hi, lo;
            bf16_split(v, hi, lo);
            Chi[(size_t)row * ldc + col0 + colL] = hi;
            Clo[(size_t)row * ldc + col0 + colL] = lo;
          } else {
            C[(size_t)row * ldc + col0 + colL] = v;
          }
        }
      }
    }
  }
}

__global__ __launch_bounds__(256)
void gemm_l1_mfma(const unsigned short* __restrict__ xa_hi,
                  const unsigned short* __restrict__ xa_lo,
                  const unsigned short* __restrict__ W1t_hi,
                  const unsigned short* __restrict__ W1t_lo,
                  const float* __restrict__ biascat,
                  unsigned short* __restrict__ h1_hi, unsigned short* __restrict__ h1_lo,
                  int M, int npad) {
  int z = blockIdx.z;
  size_t ap = (size_t)z * npad * 128;
  gemm_mfma_body<true>(xa_hi + ap, xa_lo + ap, 128,
                       W1t_hi + z * 16384, W1t_lo + z * 16384, 0,
                       nullptr, 512, z * 128, h1_hi, h1_lo,
                       biascat + z * 128, M, blockIdx.x * 128);
}

__global__ __launch_bounds__(256)
void gemm_f32out(const unsigned short* __restrict__ Ah, const unsigned short* __restrict__ Al,
                 int K, const unsigned short* __restrict__ Bh,
                 const unsigned short* __restrict__ Bl, float* __restrict__ C, int ldc,
                 int M) {
  gemm_mfma_body<false>(Ah, Al, K, Bh, Bl, blockIdx.y * 128,
                        C, ldc, blockIdx.y * 128, nullptr, nullptr, nullptr, M,
                        blockIdx.x * 128);
}

// ---------------- layers 2/3 aggregation, 4-edge unrolled ---------------------
template <int VEC, bool RELU, bool OUTSPLIT>
__global__ __launch_bounds__(64)
void agg1_kernel(const float* __restrict__ hin, float* __restrict__ out,
                 unsigned short* __restrict__ ohi, unsigned short* __restrict__ olo,
                 const int* __restrict__ rowptr, const int* __restrict__ csr_src,
                 const float* __restrict__ norm1, const float* __restrict__ dis1,
                 const float* __restrict__ bias, int n) {
  constexpr int DOUT = VEC * 64;
  int d = blockIdx.x;
  int t = threadIdx.x;
  float dd = dis1[d];
  float acc[VEC];
  {
    float sw = dd * dd;
#pragma unroll
    for (int k = 0; k < VEC; ++k) acc[k] = hin[(size_t)d * DOUT + t * VEC + k] * sw;
  }
  int beg = rowptr[d], end = rowptr[d + 1];
  int i = beg;
  for (; i + 4 <= end; i += 4) {
    int s0 = csr_src[i], s1 = csr_src[i + 1], s2 = csr_src[i + 2], s3 = csr_src[i + 3];
    float m0 = norm1[i], m1 = norm1[i + 1], m2 = norm1[i + 2], m3 = norm1[i + 3];
    if (VEC == 4) {
      float4 h0 = *(const float4*)&hin[(size_t)s0 * DOUT + t * 4];
      float4 h1 = *(const float4*)&hin[(size_t)s1 * DOUT + t * 4];
      float4 h2 = *(const float4*)&hin[(size_t)s2 * DOUT + t * 4];
      float4 h3 = *(const float4*)&hin[(size_t)s3 * DOUT + t * 4];
      acc[0] += h0.x * m0; acc[1] += h0.y * m0; acc[2 % VEC] += h0.z * m0; acc[3 % VEC] += h0.w * m0;
      acc[0] += h1.x * m1; acc[1] += h1.y * m1; acc[2 % VEC] += h1.z * m1; acc[3 % VEC] += h1.w * m1;
      acc[0] += h2.x * m2; acc[1] += h2.y * m2; acc[2 % VEC] += h2.z * m2; acc[3 % VEC] += h2.w * m2;
      acc[0] += h3.x * m3; acc[1] += h3.y * m3; acc[2 % VEC] += h3.z * m3; acc[3 % VEC] += h3.w * m3;
    } else {
      float2 h0 = *(const float2*)&hin[(size_t)s0 * DOUT + t * 2];
      float2 h1 = *(const float2*)&hin[(size_t)s1 * DOUT + t * 2];
      float2 h2 = *(const float2*)&hin[(size_t)s2 * DOUT + t * 2];
      float2 h3 = *(const float2*)&hin[(size_t)s3 * DOUT + t * 2];
      acc[0] += h0.x * m0; acc[1 % VEC] += h0.y * m0;
      acc[0] += h1.x * m1; acc[1 % VEC] += h1.y * m1;
      acc[0] += h2.x * m2; acc[1 % VEC] += h2.y * m2;
      acc[0] += h3.x * m3; acc[1 % VEC] += h3.y * m3;
    }
  }
  for (; i < end; ++i) {
    int s = csr_src[i];
    float nrm = norm1[i];
    if (VEC == 4) {
      float4 h = *(const float4*)&hin[(size_t)s * DOUT + t * 4];
      acc[0] += h.x * nrm; acc[1] += h.y * nrm;
      acc[2 % VEC] += h.z * nrm; acc[3 % VEC] += h.w * nrm;
    } else {
      float2 h = *(const float2*)&hin[(size_t)s * DOUT + t * 2];
      acc[0] += h.x * nrm; acc[1 % VEC] += h.y * nrm;
    }
  }
#pragma unroll
  for (int k = 0; k < VEC; ++k) {
    float r = acc[k] + bias[t * VEC + k];
    if (RELU) r = fmaxf(r, 0.0f);
    if (OUTSPLIT) {
      unsigned short hi, lo;
      bf16_split(r, hi, lo);
      ohi[(size_t)d * DOUT + t * VEC + k] = hi;
      olo[(size_t)d * DOUT + t * VEC + k] = lo;
    } else {
      out[(size_t)d * DOUT + t * VEC + k] = r;
    }
  }
}

// ---------------- pooling: per-graph sum + max (encoded uint) -----------------
__global__ __launch_bounds__(128)
void pool_kernel(const float* __restrict__ h3, const int* __restrict__ batch,
                 float* __restrict__ gsum, unsigned* __restrict__ gmax, int n) {
  int c = threadIdx.x;
  int start = blockIdx.x * 32;
  int end = min(start + 32, n);
  int curg = -1;
  float s = 0.0f, m = -3.402823466e38f;
  for (int i = start; i < end; ++i) {
    int g = batch[i];
    if (g != curg) {
      if (curg >= 0) {
        atomicAdd(&gsum[curg * 128 + c], s);
        atomicMax(&gmax[curg * 128 + c], fencode(m));
      }
      curg = g; s = 0.0f; m = -3.402823466e38f;
    }
    float v = h3[(size_t)i * 128 + c];
    s += v;
    m = fmaxf(m, v);
  }
  if (curg >= 0) {
    atomicAdd(&gsum[curg * 128 + c], s);
    atomicMax(&gmax[curg * 128 + c], fencode(m));
  }
}

// ---------------- final MLP; per-graph counts via binary search ---------------
__global__ __launch_bounds__(512)
void mlp_kernel(const float* __restrict__ gsum, const unsigned* __restrict__ gmax,
                const int* __restrict__ batch, int n, const float* __restrict__ Wm1,
                const float* __restrict__ bm1, const float* __restrict__ Wm2,
                const float* __restrict__ bm2, float* __restrict__ out) {
  __shared__ float hid[64][8];
  int t = threadIdx.x;
  int gi = t >> 3, u = t & 7;
  auto lb = [&](int key) {
    int lo = 0, hi = n;
    while (lo < hi) {
      int mid = (lo + hi) >> 1;
      if (batch[mid] < key) lo = mid + 1; else hi = mid;
    }
    return lo;
  };
  int cnt = lb(gi + 1) - lb(gi);
  float inv = 1.0f / fmaxf((float)cnt, 1.0f);
  float s = bm1[u];
  for (int k = 0; k < 128; ++k) {
    float mean = gsum[gi * 128 + k] * inv;
    s += mean * Wm1[k * 8 + u];
  }
  for (int k = 0; k < 128; ++k) {
    float mx = (cnt > 0) ? fdecode(gmax[gi * 128 + k]) : 0.0f;
    s += mx * Wm1[(128 + k) * 8 + u];
  }
  hid[gi][u] = fmaxf(s, 0.0f);
  __syncthreads();
  if (t < 128) {
    int g2 = t >> 1, o = t & 1;
    float s2 = bm2[o];
#pragma unroll
    for (int uu = 0; uu < 8; ++uu) s2 += hid[g2][uu] * Wm2[uu * 2 + o];
    out[g2 * 2 + o] = s2;
  }
}

extern "C" void kernel_launch(void* const* d_in, const int* in_sizes, int n_in,
                              void* d_out, int out_size, void* d_ws, size_t ws_size,
                              hipStream_t stream) {
  const float* x     = (const float*)d_in[0];
  const int*   ei    = (const int*)d_in[1];
  const float* eattr = (const float*)d_in[2];
  const int*   batch = (const int*)d_in[3];
  const float* W1A = (const float*)d_in[4],  *b1A = (const float*)d_in[5];
  const float* W1B = (const float*)d_in[6],  *b1B = (const float*)d_in[7];
  const float* W1C = (const float*)d_in[8],  *b1C = (const float*)d_in[9];
  const float* W1D = (const float*)d_in[10], *b1D = (const float*)d_in[11];
  const float* W2  = (const float*)d_in[12], *b2  = (const float*)d_in[13];
  const float* W3  = (const float*)d_in[14], *b3  = (const float*)d_in[15];
  const float* Wm1 = (const float*)d_in[16], *bm1 = (const float*)d_in[17];
  const float* Wm2 = (const float*)d_in[18], *bm2 = (const float*)d_in[19];
  float* out = (float*)d_out;

  const int n = in_sizes[0] / 128;
  const int E = in_sizes[1] / 2;
  const int npad = (n + 127) & ~127;
  const int nmb = npad / 128;

  char* ws = (char*)d_ws;
  size_t off = 0;
  auto alloc = [&](size_t bytes) -> void* {
    void* p = ws + off;
    off += (bytes + 255) & ~(size_t)255;
    return p;
  };

  float*    dis     = (float*)alloc((size_t)5 * n * 4);
  int*      rowptr  = (int*)alloc(((size_t)n + 1) * 4);
  int*      rowwork = (int*)alloc((size_t)n * 4);
  int*      local   = (int*)alloc((size_t)n * 4);
  int*      bsum    = (int*)alloc(256 * 4);
  // ---- zero block start ----
  size_t zoff = off;
  int*      cnt     = (int*)alloc((size_t)n * 4);
  float*    gsum    = (float*)alloc(64 * 128 * 4);
  unsigned* gmax    = (unsigned*)alloc(64 * 128 * 4);
  size_t zbytes = off - zoff;
  // ---- zero block end ----
  int*      csr     = (int*)alloc((size_t)E * 4);
  int*      csr_src = (int*)alloc((size_t)E * 4);
  int*      csr_dst = (int*)alloc((size_t)E * 4);
  float4*   norm4   = (float4*)alloc((size_t)E * 16);
  float*    norm1   = (float*)alloc((size_t)E * 4);
  unsigned short* W1t_hi = (unsigned short*)alloc(65536 * 2);
  unsigned short* W1t_lo = (unsigned short*)alloc(65536 * 2);
  unsigned short* W2t_hi = (unsigned short*)alloc(131072 * 2);
  unsigned short* W2t_lo = (unsigned short*)alloc(131072 * 2);
  unsigned short* W3t_hi = (unsigned short*)alloc(32768 * 2);
  unsigned short* W3t_lo = (unsigned short*)alloc(32768 * 2);
  float*    biascat = (float*)alloc(512 * 4);
  unsigned short* xa_hi = (unsigned short*)alloc((size_t)4 * npad * 128 * 2);
  unsigned short* xa_lo = (unsigned short*)alloc((size_t)4 * npad * 128 * 2);
  unsigned short* h1_hi = (unsigned short*)alloc((size_t)npad * 512 * 2);
  unsigned short* h1_lo = (unsigned short*)alloc((size_t)npad * 512 * 2);

  // lifetime-safe reuse:
  float* h2pre = (float*)xa_hi;                 // [npad,256] fp32
  float* h3pre = (float*)xa_lo;                 // [npad,128] fp32
  unsigned short* h2_hi = h1_hi;                // [npad,256]
  unsigned short* h2_lo = h1_hi + (size_t)npad * 256;
  float* h3 = (float*)h1_lo;                    // [npad,128] fp32

  hipMemsetAsync(ws + zoff, 0, zbytes, stream);

  prep_kernel<<<(229888 + 255) / 256, 256, 0, stream>>>(
      W1A, W1B, W1C, W1D, b1A, b1B, b1C, b1D, W2, W3,
      W1t_hi, W1t_lo, W2t_hi, W2t_lo, W3t_hi, W3t_lo, biascat);

  int nb = (n + 255) / 256;
  hist_kernel<<<(E + 255) / 256, 256, 0, stream>>>(ei, cnt, E);
  scan1_kernel<<<nb, 256, 0, stream>>>(cnt, local, bsum, n);
  scan2_kernel<<<1, 256, 0, stream>>>(bsum, nb);
  scan3_kernel<<<nb, 256, 0, stream>>>(local, bsum, rowptr, rowwork, n, E);
  fill_kernel<<<(E + 255) / 256, 256, 0, stream>>>(ei, rowwork, csr, csr_src, csr_dst, E);
  degcsr_kernel<<<(n + 255) / 256, 256, 0, stream>>>(rowptr, csr, eattr, dis, n);
  edgeprep_kernel<<<(E + 255) / 256, 256, 0, stream>>>(csr, csr_src, csr_dst, eattr,
                                                       dis, norm4, norm1, n, E);

  // layer 1
  agg4x_kernel<<<n, 64, 0, stream>>>(x, xa_hi, xa_lo, rowptr, csr_src, norm4, dis, n, npad);
  gemm_l1_mfma<<<dim3(nmb, 1, 4), 256, 0, stream>>>(xa_hi, xa_lo, W1t_hi, W1t_lo,
                                                    biascat, h1_hi, h1_lo, n, npad);
  // layer 2
  gemm_f32out<<<dim3(nmb, 2), 256, 0, stream>>>(h1_hi, h1_lo, 512, W2t_hi, W2t_lo,
                                                h2pre, 256, n);
  agg1_kernel<4, true, true><<<n, 64, 0, stream>>>(h2pre, nullptr, h2_hi, h2_lo,
                                                   rowptr, csr_src, norm1,
                                                   dis + (size_t)4 * n, b2, n);
  // layer 3
  gemm_f32out<<<dim3(nmb, 1), 256, 0, stream>>>(h2_hi, h2_lo, 256, W3t_hi, W3t_lo,
                                                h3pre, 128, n);
  agg1_kernel<2, false, false><<<n, 64, 0, stream>>>(h3pre, h3, nullptr, nullptr,
                                                     rowptr, csr_src, norm1,
                                                     dis + (size_t)4 * n, b3, n);

  pool_kernel<<<(n + 31) / 32, 128, 0, stream>>>(h3, batch, gsum, gmax, n);
  mlp_kernel<<<1, 512, 0, stream>>>(gsum, gmax, batch, n, Wm1, bm1, Wm2, bm2, out);
}

// Round 5
// 557.710 us; speedup vs baseline: 2.5768x; 1.1317x over previous
//
#include <hip/hip_runtime.h>

#define DEV_INLINE __device__ __forceinline__

typedef __attribute__((ext_vector_type(8))) short bf16x8;
typedef __attribute__((ext_vector_type(4))) float floatx4;

DEV_INLINE unsigned fencode(float f) {
  unsigned u = __float_as_uint(f);
  return (u & 0x80000000u) ? ~u : (u | 0x80000000u);
}
DEV_INLINE float fdecode(unsigned k) {
  return __uint_as_float((k & 0x80000000u) ? (k ^ 0x80000000u) : ~k);
}

DEV_INLINE unsigned short bf16_rne(float x) {
  unsigned u = __float_as_uint(x);
  unsigned r = (u + 0x7FFFu + ((u >> 16) & 1u)) >> 16;
  return (unsigned short)r;
}
DEV_INLINE void bf16_split(float x, unsigned short& hi, unsigned short& lo) {
  hi = bf16_rne(x);
  float hf = __uint_as_float(((unsigned)hi) << 16);
  lo = bf16_rne(x - hf);
}
DEV_INLINE float bf2f(unsigned short u) {
  return __uint_as_float(((unsigned)u) << 16);
}

#pragma clang diagnostic ignored "-Waddress-space-conversion"
DEV_INLINE void gload_lds16(const void* g, void* l) {
  __builtin_amdgcn_global_load_lds(
      (const __attribute__((address_space(1))) unsigned int*)g,
      (__attribute__((address_space(3))) unsigned int*)l, 16, 0, 0);
}

// ---------------- prep: transpose+split weights to bf16 hi/lo [N][K] planes ---
__global__ __launch_bounds__(256)
void prep_kernel(const float* __restrict__ WA, const float* __restrict__ WB,
                 const float* __restrict__ WC, const float* __restrict__ WD,
                 const float* __restrict__ bA, const float* __restrict__ bB,
                 const float* __restrict__ bC, const float* __restrict__ bD,
                 const float* __restrict__ W2, const float* __restrict__ W3,
                 unsigned short* __restrict__ W1t_hi, unsigned short* __restrict__ W1t_lo,
                 unsigned short* __restrict__ W2t_hi, unsigned short* __restrict__ W2t_lo,
                 unsigned short* __restrict__ W3t_hi, unsigned short* __restrict__ W3t_lo,
                 float* __restrict__ biascat) {
  int i = blockIdx.x * 256 + threadIdx.x;
  if (i < 65536) {  // W1 planes: [z][j out][k in]
    int z = i >> 14, rem = i & 16383, j = rem >> 7, k = rem & 127;
    const float* W = (z == 0) ? WA : (z == 1) ? WB : (z == 2) ? WC : WD;
    unsigned short hi, lo;
    bf16_split(W[k * 128 + j], hi, lo);
    W1t_hi[i] = hi; W1t_lo[i] = lo;
  } else if (i < 196608) {  // W2t [256][512]
    int i2 = i - 65536, j = i2 >> 9, k = i2 & 511;
    unsigned short hi, lo;
    bf16_split(W2[k * 256 + j], hi, lo);
    W2t_hi[i2] = hi; W2t_lo[i2] = lo;
  } else if (i < 229376) {  // W3t [128][256]
    int i3 = i - 196608, j = i3 >> 8, k = i3 & 255;
    unsigned short hi, lo;
    bf16_split(W3[k * 128 + j], hi, lo);
    W3t_hi[i3] = hi; W3t_lo[i3] = lo;
  } else if (i < 229888) {
    int i4 = i - 229376, c = i4 >> 7, j = i4 & 127;
    const float* b = (c == 0) ? bA : (c == 1) ? bB : (c == 2) ? bC : bD;
    biascat[i4] = b[j];
  }
}

// ---------------- x -> bf16 cast ----------------------------------------------
__global__ __launch_bounds__(256)
void xcast_kernel(const float* __restrict__ x, unsigned short* __restrict__ xb, int total4) {
  int i = blockIdx.x * 256 + threadIdx.x;
  if (i >= total4) return;
  float4 v = ((const float4*)x)[i];
  ushort4 o;
  o.x = bf16_rne(v.x); o.y = bf16_rne(v.y); o.z = bf16_rne(v.z); o.w = bf16_rne(v.w);
  ((ushort4*)xb)[i] = o;
}

// ---------------- in-degree histogram ----------------------------------------
__global__ __launch_bounds__(256)
void hist_kernel(const int* __restrict__ ei, int* __restrict__ cnt, int E) {
  int e = blockIdx.x * 256 + threadIdx.x;
  if (e < E) atomicAdd(&cnt[ei[E + e]], 1);
}

// ---------------- 3-level exclusive scan -------------------------------------
__global__ __launch_bounds__(256)
void scan1_kernel(const int* __restrict__ cnt, int* __restrict__ local,
                  int* __restrict__ bsum, int n) {
  __shared__ int s[256];
  int tid = threadIdx.x;
  int i = blockIdx.x * 256 + tid;
  int v = (i < n) ? cnt[i] : 0;
  s[tid] = v;
  __syncthreads();
#pragma unroll
  for (int off = 1; off < 256; off <<= 1) {
    int t = (tid >= off) ? s[tid - off] : 0;
    __syncthreads();
    s[tid] += t;
    __syncthreads();
  }
  if (i < n) local[i] = s[tid] - v;
  if (tid == 255) bsum[blockIdx.x] = s[255];
}

__global__ __launch_bounds__(256)
void scan2_kernel(int* __restrict__ bsum, int nb) {
  __shared__ int s[256];
  int tid = threadIdx.x;
  int v = (tid < nb) ? bsum[tid] : 0;
  s[tid] = v;
  __syncthreads();
#pragma unroll
  for (int off = 1; off < 256; off <<= 1) {
    int t = (tid >= off) ? s[tid - off] : 0;
    __syncthreads();
    s[tid] += t;
    __syncthreads();
  }
  if (tid < nb) bsum[tid] = s[tid] - v;  // exclusive
}

__global__ __launch_bounds__(256)
void scan3_kernel(const int* __restrict__ local, const int* __restrict__ bsum,
                  int* __restrict__ rowptr, int* __restrict__ rowwork, int n, int E) {
  int i = blockIdx.x * 256 + threadIdx.x;
  if (i < n) {
    int rp = local[i] + bsum[blockIdx.x];
    rowptr[i] = rp;
    rowwork[i] = rp;
  }
  if (i == 0) rowptr[n] = E;
}

// ---------------- CSR fill (also writes src/dst per slot) ---------------------
__global__ __launch_bounds__(256)
void fill_kernel(const int* __restrict__ ei, int* __restrict__ rowwork,
                 int* __restrict__ csr, int* __restrict__ csr_src,
                 int* __restrict__ csr_dst, int E) {
  int e = blockIdx.x * 256 + threadIdx.x;
  if (e >= E) return;
  int d = ei[E + e];
  int pos = atomicAdd(&rowwork[d], 1);
  csr[pos] = e;
  csr_src[pos] = ei[e];
  csr_dst[pos] = d;
}

// ---------------- degrees from CSR (node-centric, fused rsqrt) ----------------
__global__ __launch_bounds__(256)
void degcsr_kernel(const int* __restrict__ rowptr, const int* __restrict__ csr,
                   const float* __restrict__ eattr, float* __restrict__ dis, int n) {
  int d = blockIdx.x * 256 + threadIdx.x;
  if (d >= n) return;
  int beg = rowptr[d], end = rowptr[d + 1];
  float s0 = 1.f, s1 = 1.f, s2 = 1.f, s3 = 1.f;  // self-loop weight 1
  for (int i = beg; i < end; ++i) {
    int e = csr[i];
    float4 w = ((const float4*)eattr)[e];
    s0 += w.x; s1 += w.y; s2 += w.z; s3 += w.w;
  }
  dis[d]         = 1.0f / sqrtf(s0);
  dis[n + d]     = 1.0f / sqrtf(s1);
  dis[2 * n + d] = 1.0f / sqrtf(s2);
  dis[3 * n + d] = 1.0f / sqrtf(s3);
  dis[4 * n + d] = 1.0f / sqrtf(1.0f + (float)(end - beg));
}

// ---------------- per-CSR-slot norms -------------------------------------------
__global__ __launch_bounds__(256)
void edgeprep_kernel(const int* __restrict__ csr, const int* __restrict__ csr_src,
                     const int* __restrict__ csr_dst, const float* __restrict__ eattr,
                     const float* __restrict__ dis, float4* __restrict__ norm4,
                     float* __restrict__ norm1, int n, int E) {
  int i = blockIdx.x * 256 + threadIdx.x;
  if (i >= E) return;
  int e = csr[i], s = csr_src[i], d = csr_dst[i];
  float4 w = ((const float4*)eattr)[e];
  float4 o;
  o.x = dis[s] * w.x * dis[d];
  o.y = dis[n + s] * w.y * dis[n + d];
  o.z = dis[2 * n + s] * w.z * dis[2 * n + d];
  o.w = dis[3 * n + s] * w.w * dis[3 * n + d];
  norm4[i] = o;
  norm1[i] = dis[4 * n + s] * dis[4 * n + d];
}

// ---------------- layer-1 aggregation on bf16 x; split output ------------------
// 256 thr = 4 waves; wave w handles node blockIdx*4+w; lane t: cols 2t,2t+1
__global__ __launch_bounds__(256)
void agg4x_kernel(const unsigned short* __restrict__ xb,
                  unsigned short* __restrict__ xa_hi, unsigned short* __restrict__ xa_lo,
                  const int* __restrict__ rowptr, const int* __restrict__ csr_src,
                  const float4* __restrict__ norm4, const float* __restrict__ dis,
                  int n, int npad) {
  int d = blockIdx.x * 4 + (threadIdx.x >> 6);
  if (d >= n) return;
  int t = threadIdx.x & 63;
  float dc0 = dis[d], dc1 = dis[n + d], dc2 = dis[2 * n + d], dc3 = dis[3 * n + d];
  const ushort2* x2 = (const ushort2*)xb;
  ushort2 xu = x2[(size_t)d * 64 + t];
  float xvx = bf2f(xu.x), xvy = bf2f(xu.y);
  float a0x = xvx * dc0 * dc0, a0y = xvy * dc0 * dc0;
  float a1x = xvx * dc1 * dc1, a1y = xvy * dc1 * dc1;
  float a2x = xvx * dc2 * dc2, a2y = xvy * dc2 * dc2;
  float a3x = xvx * dc3 * dc3, a3y = xvy * dc3 * dc3;
  int beg = rowptr[d], end = rowptr[d + 1];
  int i = beg;
  for (; i + 4 <= end; i += 4) {
    int s0 = csr_src[i], s1 = csr_src[i + 1], s2 = csr_src[i + 2], s3 = csr_src[i + 3];
    float4 m0 = norm4[i], m1 = norm4[i + 1], m2 = norm4[i + 2], m3 = norm4[i + 3];
    ushort2 u0 = x2[(size_t)s0 * 64 + t];
    ushort2 u1 = x2[(size_t)s1 * 64 + t];
    ushort2 u2 = x2[(size_t)s2 * 64 + t];
    ushort2 u3 = x2[(size_t)s3 * 64 + t];
    float h0x = bf2f(u0.x), h0y = bf2f(u0.y);
    float h1x = bf2f(u1.x), h1y = bf2f(u1.y);
    float h2x = bf2f(u2.x), h2y = bf2f(u2.y);
    float h3x = bf2f(u3.x), h3y = bf2f(u3.y);
    a0x += h0x * m0.x; a0y += h0y * m0.x;
    a1x += h0x * m0.y; a1y += h0y * m0.y;
    a2x += h0x * m0.z; a2y += h0y * m0.z;
    a3x += h0x * m0.w; a3y += h0y * m0.w;
    a0x += h1x * m1.x; a0y += h1y * m1.x;
    a1x += h1x * m1.y; a1y += h1y * m1.y;
    a2x += h1x * m1.z; a2y += h1y * m1.z;
    a3x += h1x * m1.w; a3y += h1y * m1.w;
    a0x += h2x * m2.x; a0y += h2y * m2.x;
    a1x += h2x * m2.y; a1y += h2y * m2.y;
    a2x += h2x * m2.z; a2y += h2y * m2.z;
    a3x += h2x * m2.w; a3y += h2y * m2.w;
    a0x += h3x * m3.x; a0y += h3y * m3.x;
    a1x += h3x * m3.y; a1y += h3y * m3.y;
    a2x += h3x * m3.z; a2y += h3y * m3.z;
    a3x += h3x * m3.w; a3y += h3y * m3.w;
  }
  for (; i < end; ++i) {
    int s = csr_src[i];
    float4 m = norm4[i];
    ushort2 u = x2[(size_t)s * 64 + t];
    float hx = bf2f(u.x), hy = bf2f(u.y);
    a0x += hx * m.x; a0y += hy * m.x;
    a1x += hx * m.y; a1y += hy * m.y;
    a2x += hx * m.z; a2y += hy * m.z;
    a3x += hx * m.w; a3y += hy * m.w;
  }
  size_t plane = (size_t)npad * 128;
  size_t base = (size_t)d * 128 + 2 * t;
  float vx[4] = {a0x, a1x, a2x, a3x};
  float vy[4] = {a0y, a1y, a2y, a3y};
#pragma unroll
  for (int z = 0; z < 4; ++z) {
    unsigned short hx, lx, hy, ly;
    bf16_split(vx[z], hx, lx);
    bf16_split(vy[z], hy, ly);
    ushort2 h2v; h2v.x = hx; h2v.y = hy;
    ushort2 l2v; l2v.x = lx; l2v.y = ly;
    *(ushort2*)&xa_hi[plane * z + base] = h2v;
    *(ushort2*)&xa_lo[plane * z + base] = l2v;
  }
}

// ---------------- MFMA split-bf16 GEMM body -----------------------------------
// MODE 0: fp32 C. MODE 1: split hi/lo + bias + relu. MODE 2: bf16 C (Chi).
template <int MODE>
DEV_INLINE void gemm_mfma_body(const unsigned short* __restrict__ Ah,
                               const unsigned short* __restrict__ Al, int K,
                               const unsigned short* __restrict__ Bh,
                               const unsigned short* __restrict__ Bl, int nTile0,
                               float* __restrict__ C, int ldc, int col0,
                               unsigned short* __restrict__ Chi,
                               unsigned short* __restrict__ Clo,
                               const float* __restrict__ bias, int M, int row0) {
  __shared__ __align__(16) unsigned short As[2][128 * 32];
  __shared__ __align__(16) unsigned short Bs[2][128 * 32];
  int tid = threadIdx.x;
  int w = tid >> 6, lane = tid & 63;
  int quad = lane >> 4, lrow = lane & 15;
  int wm = (w >> 1) * 64, wn = (w & 1) * 64;
  int srow = lane >> 2;
  int scol8 = (lane & 3) * 8;

  floatx4 zero4 = {0.f, 0.f, 0.f, 0.f};
  floatx4 acc[4][4];
#pragma unroll
  for (int i = 0; i < 4; ++i)
#pragma unroll
    for (int j = 0; j < 4; ++j) acc[i][j] = zero4;

  for (int k0 = 0; k0 < K; k0 += 32) {
#pragma unroll
    for (int q = 0; q < 2; ++q) {
      int r = w * 32 + q * 16 + srow;
      size_t ga = (size_t)(row0 + r) * K + k0 + scol8;
      size_t gb = (size_t)(nTile0 + r) * K + k0 + scol8;
      int lo = (w * 32 + q * 16) * 32;
      gload_lds16(Ah + ga, &As[0][lo]);
      gload_lds16(Al + ga, &As[1][lo]);
      gload_lds16(Bh + gb, &Bs[0][lo]);
      gload_lds16(Bl + gb, &Bs[1][lo]);
    }
    __syncthreads();
    bf16x8 ah[4], al[4];
#pragma unroll
    for (int i = 0; i < 4; ++i) {
      int off = (wm + i * 16 + lrow) * 32 + quad * 8;
      ah[i] = *(const bf16x8*)&As[0][off];
      al[i] = *(const bf16x8*)&As[1][off];
    }
#pragma unroll
    for (int j = 0; j < 4; ++j) {
      int off = (wn + j * 16 + lrow) * 32 + quad * 8;
      bf16x8 bh = *(const bf16x8*)&Bs[0][off];
      bf16x8 bl = *(const bf16x8*)&Bs[1][off];
#pragma unroll
      for (int i = 0; i < 4; ++i) {
        acc[i][j] = __builtin_amdgcn_mfma_f32_16x16x32_bf16(ah[i], bh, acc[i][j], 0, 0, 0);
        acc[i][j] = __builtin_amdgcn_mfma_f32_16x16x32_bf16(ah[i], bl, acc[i][j], 0, 0, 0);
        acc[i][j] = __builtin_amdgcn_mfma_f32_16x16x32_bf16(al[i], bh, acc[i][j], 0, 0, 0);
      }
    }
    __syncthreads();
  }
#pragma unroll
  for (int i = 0; i < 4; ++i) {
#pragma unroll
    for (int j = 0; j < 4; ++j) {
      int colL = wn + j * 16 + lrow;
#pragma unroll
      for (int r = 0; r < 4; ++r) {
        int row = row0 + wm + i * 16 + quad * 4 + r;
        if (row < M) {
          float v = acc[i][j][r];
          if (MODE == 1) {
            v = fmaxf(v + bias[colL], 0.0f);
            unsigned short hi, lo;
            bf16_split(v, hi, lo);
            Chi[(size_t)row * ldc + col0 + colL] = hi;
            Clo[(size_t)row * ldc + col0 + colL] = lo;
          } else if (MODE == 2) {
            Chi[(size_t)row * ldc + col0 + colL] = bf16_rne(v);
          } else {
            C[(size_t)row * ldc + col0 + colL] = v;
          }
        }
      }
    }
  }
}

__global__ __launch_bounds__(256)
void gemm_l1_mfma(const unsigned short* __restrict__ xa_hi,
                  const unsigned short* __restrict__ xa_lo,
                  const unsigned short* __restrict__ W1t_hi,
                  const unsigned short* __restrict__ W1t_lo,
                  const float* __restrict__ biascat,
                  unsigned short* __restrict__ h1_hi, unsigned short* __restrict__ h1_lo,
                  int M, int npad) {
  int z = blockIdx.z;
  size_t ap = (size_t)z * npad * 128;
  gemm_mfma_body<1>(xa_hi + ap, xa_lo + ap, 128,
                    W1t_hi + z * 16384, W1t_lo + z * 16384, 0,
                    nullptr, 512, z * 128, h1_hi, h1_lo,
                    biascat + z * 128, M, blockIdx.x * 128);
}

__global__ __launch_bounds__(256)
void gemm_bf16out(const unsigned short* __restrict__ Ah, const unsigned short* __restrict__ Al,
                  int K, const unsigned short* __restrict__ Bh,
                  const unsigned short* __restrict__ Bl, unsigned short* __restrict__ Cb,
                  int ldc, int M) {
  gemm_mfma_body<2>(Ah, Al, K, Bh, Bl, blockIdx.y * 128,
                    nullptr, ldc, blockIdx.y * 128, Cb, nullptr, nullptr, M,
                    blockIdx.x * 128);
}

// ---------------- layers 2/3 aggregation: bf16 gather, 4-edge unroll ----------
// 256 thr = 4 waves; wave handles one node. VEC = bf16 elems per lane.
template <int VEC, bool RELU, bool OUTSPLIT>
__global__ __launch_bounds__(256)
void agg1_kernel(const unsigned short* __restrict__ hb, float* __restrict__ out,
                 unsigned short* __restrict__ ohi, unsigned short* __restrict__ olo,
                 const int* __restrict__ rowptr, const int* __restrict__ csr_src,
                 const float* __restrict__ norm1, const float* __restrict__ dis1,
                 const float* __restrict__ bias, int n) {
  constexpr int DOUT = VEC * 64;
  int d = blockIdx.x * 4 + (threadIdx.x >> 6);
  if (d >= n) return;
  int t = threadIdx.x & 63;
  float dd = dis1[d];
  float acc[VEC];
  {
    float sw = dd * dd;
#pragma unroll
    for (int k = 0; k < VEC; ++k) acc[k] = bf2f(hb[(size_t)d * DOUT + t * VEC + k]) * sw;
  }
  int beg = rowptr[d], end = rowptr[d + 1];
  int i = beg;
  for (; i + 4 <= end; i += 4) {
    int s0 = csr_src[i], s1 = csr_src[i + 1], s2 = csr_src[i + 2], s3 = csr_src[i + 3];
    float m0 = norm1[i], m1 = norm1[i + 1], m2 = norm1[i + 2], m3 = norm1[i + 3];
    if (VEC == 4) {
      ushort4 u0 = *(const ushort4*)&hb[(size_t)s0 * DOUT + t * 4];
      ushort4 u1 = *(const ushort4*)&hb[(size_t)s1 * DOUT + t * 4];
      ushort4 u2 = *(const ushort4*)&hb[(size_t)s2 * DOUT + t * 4];
      ushort4 u3 = *(const ushort4*)&hb[(size_t)s3 * DOUT + t * 4];
      acc[0] += bf2f(u0.x) * m0; acc[1] += bf2f(u0.y) * m0;
      acc[2 % VEC] += bf2f(u0.z) * m0; acc[3 % VEC] += bf2f(u0.w) * m0;
      acc[0] += bf2f(u1.x) * m1; acc[1] += bf2f(u1.y) * m1;
      acc[2 % VEC] += bf2f(u1.z) * m1; acc[3 % VEC] += bf2f(u1.w) * m1;
      acc[0] += bf2f(u2.x) * m2; acc[1] += bf2f(u2.y) * m2;
      acc[2 % VEC] += bf2f(u2.z) * m2; acc[3 % VEC] += bf2f(u2.w) * m2;
      acc[0] += bf2f(u3.x) * m3; acc[1] += bf2f(u3.y) * m3;
      acc[2 % VEC] += bf2f(u3.z) * m3; acc[3 % VEC] += bf2f(u3.w) * m3;
    } else {
      ushort2 u0 = *(const ushort2*)&hb[(size_t)s0 * DOUT + t * 2];
      ushort2 u1 = *(const ushort2*)&hb[(size_t)s1 * DOUT + t * 2];
      ushort2 u2 = *(const ushort2*)&hb[(size_t)s2 * DOUT + t * 2];
      ushort2 u3 = *(const ushort2*)&hb[(size_t)s3 * DOUT + t * 2];
      acc[0] += bf2f(u0.x) * m0; acc[1 % VEC] += bf2f(u0.y) * m0;
      acc[0] += bf2f(u1.x) * m1; acc[1 % VEC] += bf2f(u1.y) * m1;
      acc[0] += bf2f(u2.x) * m2; acc[1 % VEC] += bf2f(u2.y) * m2;
      acc[0] += bf2f(u3.x) * m3; acc[1 % VEC] += bf2f(u3.y) * m3;
    }
  }
  for (; i < end; ++i) {
    int s = csr_src[i];
    float nrm = norm1[i];
    if (VEC == 4) {
      ushort4 u = *(const ushort4*)&hb[(size_t)s * DOUT + t * 4];
      acc[0] += bf2f(u.x) * nrm; acc[1] += bf2f(u.y) * nrm;
      acc[2 % VEC] += bf2f(u.z) * nrm; acc[3 % VEC] += bf2f(u.w) * nrm;
    } else {
      ushort2 u = *(const ushort2*)&hb[(size_t)s * DOUT + t * 2];
      acc[0] += bf2f(u.x) * nrm; acc[1 % VEC] += bf2f(u.y) * nrm;
    }
  }
#pragma unroll
  for (int k = 0; k < VEC; ++k) {
    float r = acc[k] + bias[t * VEC + k];
    if (RELU) r = fmaxf(r, 0.0f);
    if (OUTSPLIT) {
      unsigned short hi, lo;
      bf16_split(r, hi, lo);
      ohi[(size_t)d * DOUT + t * VEC + k] = hi;
      olo[(size_t)d * DOUT + t * VEC + k] = lo;
    } else {
      out[(size_t)d * DOUT + t * VEC + k] = r;
    }
  }
}

// ---------------- pooling: per-graph sum + max (encoded uint) -----------------
__global__ __launch_bounds__(128)
void pool_kernel(const float* __restrict__ h3, const int* __restrict__ batch,
                 float* __restrict__ gsum, unsigned* __restrict__ gmax, int n) {
  int c = threadIdx.x;
  int start = blockIdx.x * 32;
  int end = min(start + 32, n);
  int curg = -1;
  float s = 0.0f, m = -3.402823466e38f;
  for (int i = start; i < end; ++i) {
    int g = batch[i];
    if (g != curg) {
      if (curg >= 0) {
        atomicAdd(&gsum[curg * 128 + c], s);
        atomicMax(&gmax[curg * 128 + c], fencode(m));
      }
      curg = g; s = 0.0f; m = -3.402823466e38f;
    }
    float v = h3[(size_t)i * 128 + c];
    s += v;
    m = fmaxf(m, v);
  }
  if (curg >= 0) {
    atomicAdd(&gsum[curg * 128 + c], s);
    atomicMax(&gmax[curg * 128 + c], fencode(m));
  }
}

// ---------------- final MLP; per-graph counts via binary search ---------------
__global__ __launch_bounds__(512)
void mlp_kernel(const float* __restrict__ gsum, const unsigned* __restrict__ gmax,
                const int* __restrict__ batch, int n, const float* __restrict__ Wm1,
                const float* __restrict__ bm1, const float* __restrict__ Wm2,
                const float* __restrict__ bm2, float* __restrict__ out) {
  __shared__ float hid[64][8];
  int t = threadIdx.x;
  int gi = t >> 3, u = t & 7;
  auto lb = [&](int key) {
    int lo = 0, hi = n;
    while (lo < hi) {
      int mid = (lo + hi) >> 1;
      if (batch[mid] < key) lo = mid + 1; else hi = mid;
    }
    return lo;
  };
  int cnt = lb(gi + 1) - lb(gi);
  float inv = 1.0f / fmaxf((float)cnt, 1.0f);
  float s = bm1[u];
  for (int k = 0; k < 128; ++k) {
    float mean = gsum[gi * 128 + k] * inv;
    s += mean * Wm1[k * 8 + u];
  }
  for (int k = 0; k < 128; ++k) {
    float mx = (cnt > 0) ? fdecode(gmax[gi * 128 + k]) : 0.0f;
    s += mx * Wm1[(128 + k) * 8 + u];
  }
  hid[gi][u] = fmaxf(s, 0.0f);
  __syncthreads();
  if (t < 128) {
    int g2 = t >> 1, o = t & 1;
    float s2 = bm2[o];
#pragma unroll
    for (int uu = 0; uu < 8; ++uu) s2 += hid[g2][uu] * Wm2[uu * 2 + o];
    out[g2 * 2 + o] = s2;
  }
}

extern "C" void kernel_launch(void* const* d_in, const int* in_sizes, int n_in,
                              void* d_out, int out_size, void* d_ws, size_t ws_size,
                              hipStream_t stream) {
  const float* x     = (const float*)d_in[0];
  const int*   ei    = (const int*)d_in[1];
  const float* eattr = (const float*)d_in[2];
  const int*   batch = (const int*)d_in[3];
  const float* W1A = (const float*)d_in[4],  *b1A = (const float*)d_in[5];
  const float* W1B = (const float*)d_in[6],  *b1B = (const float*)d_in[7];
  const float* W1C = (const float*)d_in[8],  *b1C = (const float*)d_in[9];
  const float* W1D = (const float*)d_in[10], *b1D = (const float*)d_in[11];
  const float* W2  = (const float*)d_in[12], *b2  = (const float*)d_in[13];
  const float* W3  = (const float*)d_in[14], *b3  = (const float*)d_in[15];
  const float* Wm1 = (const float*)d_in[16], *bm1 = (const float*)d_in[17];
  const float* Wm2 = (const float*)d_in[18], *bm2 = (const float*)d_in[19];
  float* out = (float*)d_out;

  const int n = in_sizes[0] / 128;
  const int E = in_sizes[1] / 2;
  const int npad = (n + 127) & ~127;
  const int nmb = npad / 128;

  char* ws = (char*)d_ws;
  size_t off = 0;
  auto alloc = [&](size_t bytes) -> void* {
    void* p = ws + off;
    off += (bytes + 255) & ~(size_t)255;
    return p;
  };

  float*    dis     = (float*)alloc((size_t)5 * n * 4);
  int*      rowptr  = (int*)alloc(((size_t)n + 1) * 4);
  int*      rowwork = (int*)alloc((size_t)n * 4);
  int*      local   = (int*)alloc((size_t)n * 4);
  int*      bsum    = (int*)alloc(256 * 4);
  // ---- zero block start ----
  size_t zoff = off;
  int*      cnt     = (int*)alloc((size_t)n * 4);
  float*    gsum    = (float*)alloc(64 * 128 * 4);
  unsigned* gmax    = (unsigned*)alloc(64 * 128 * 4);
  size_t zbytes = off - zoff;
  // ---- zero block end ----
  int*      csr     = (int*)alloc((size_t)E * 4);
  int*      csr_src = (int*)alloc((size_t)E * 4);
  int*      csr_dst = (int*)alloc((size_t)E * 4);
  float4*   norm4   = (float4*)alloc((size_t)E * 16);
  float*    norm1   = (float*)alloc((size_t)E * 4);
  unsigned short* W1t_hi = (unsigned short*)alloc(65536 * 2);
  unsigned short* W1t_lo = (unsigned short*)alloc(65536 * 2);
  unsigned short* W2t_hi = (unsigned short*)alloc(131072 * 2);
  unsigned short* W2t_lo = (unsigned short*)alloc(131072 * 2);
  unsigned short* W3t_hi = (unsigned short*)alloc(32768 * 2);
  unsigned short* W3t_lo = (unsigned short*)alloc(32768 * 2);
  float*    biascat = (float*)alloc(512 * 4);
  unsigned short* xb    = (unsigned short*)alloc((size_t)npad * 128 * 2);
  unsigned short* xa_hi = (unsigned short*)alloc((size_t)4 * npad * 128 * 2);
  unsigned short* xa_lo = (unsigned short*)alloc((size_t)4 * npad * 128 * 2);
  unsigned short* h1_hi = (unsigned short*)alloc((size_t)npad * 512 * 2);
  unsigned short* h1_lo = (unsigned short*)alloc((size_t)npad * 512 * 2);

  // lifetime-safe reuse:
  unsigned short* h2pre_b = xa_hi;              // [npad,256] bf16 (xa dead after gemm_l1)
  unsigned short* h3pre_b = xa_lo;              // [npad,128] bf16
  unsigned short* h2_hi = h1_hi;                // [npad,256] (h1 dead after gemm_l2)
  unsigned short* h2_lo = h1_hi + (size_t)npad * 256;
  float* h3 = (float*)h1_lo;                    // [npad,128] fp32 (h1_lo dead after gemm_l2)

  hipMemsetAsync(ws + zoff, 0, zbytes, stream);

  prep_kernel<<<(229888 + 255) / 256, 256, 0, stream>>>(
      W1A, W1B, W1C, W1D, b1A, b1B, b1C, b1D, W2, W3,
      W1t_hi, W1t_lo, W2t_hi, W2t_lo, W3t_hi, W3t_lo, biascat);
  xcast_kernel<<<((n * 32) + 255) / 256, 256, 0, stream>>>(x, xb, n * 32);

  int nb = (n + 255) / 256;
  hist_kernel<<<(E + 255) / 256, 256, 0, stream>>>(ei, cnt, E);
  scan1_kernel<<<nb, 256, 0, stream>>>(cnt, local, bsum, n);
  scan2_kernel<<<1, 256, 0, stream>>>(bsum, nb);
  scan3_kernel<<<nb, 256, 0, stream>>>(local, bsum, rowptr, rowwork, n, E);
  fill_kernel<<<(E + 255) / 256, 256, 0, stream>>>(ei, rowwork, csr, csr_src, csr_dst, E);
  degcsr_kernel<<<(n + 255) / 256, 256, 0, stream>>>(rowptr, csr, eattr, dis, n);
  edgeprep_kernel<<<(E + 255) / 256, 256, 0, stream>>>(csr, csr_src, csr_dst, eattr,
                                                       dis, norm4, norm1, n, E);

  int nodeblk = (n + 3) / 4;
  // layer 1
  agg4x_kernel<<<nodeblk, 256, 0, stream>>>(xb, xa_hi, xa_lo, rowptr, csr_src, norm4, dis, n, npad);
  gemm_l1_mfma<<<dim3(nmb, 1, 4), 256, 0, stream>>>(xa_hi, xa_lo, W1t_hi, W1t_lo,
                                                    biascat, h1_hi, h1_lo, n, npad);
  // layer 2
  gemm_bf16out<<<dim3(nmb, 2), 256, 0, stream>>>(h1_hi, h1_lo, 512, W2t_hi, W2t_lo,
                                                 h2pre_b, 256, n);
  agg1_kernel<4, true, true><<<nodeblk, 256, 0, stream>>>(h2pre_b, nullptr, h2_hi, h2_lo,
                                                          rowptr, csr_src, norm1,
                                                          dis + (size_t)4 * n, b2, n);
  // layer 3
  gemm_bf16out<<<dim3(nmb, 1), 256, 0, stream>>>(h2_hi, h2_lo, 256, W3t_hi, W3t_lo,
                                                 h3pre_b, 128, n);
  agg1_kernel<2, false, false><<<nodeblk, 256, 0, stream>>>(h3pre_b, h3, nullptr, nullptr,
                                                            rowptr, csr_src, norm1,
                                                            dis + (size_t)4 * n, b3, n);

  pool_kernel<<<(n + 31) / 32, 128, 0, stream>>>(h3, batch, gsum, gmax, n);
  mlp_kernel<<<1, 512, 0, stream>>>(gsum, gmax, batch, n, Wm1, bm1, Wm2, bm2, out);
}

// Round 6
// 532.637 us; speedup vs baseline: 2.6981x; 1.0471x over previous
//
#include <hip/hip_runtime.h>

#define DEV_INLINE __device__ __forceinline__

typedef __attribute__((ext_vector_type(8))) short bf16x8;
typedef __attribute__((ext_vector_type(4))) float floatx4;

DEV_INLINE unsigned fencode(float f) {
  unsigned u = __float_as_uint(f);
  return (u & 0x80000000u) ? ~u : (u | 0x80000000u);
}
DEV_INLINE float fdecode(unsigned k) {
  return __uint_as_float((k & 0x80000000u) ? (k ^ 0x80000000u) : ~k);
}

DEV_INLINE unsigned short bf16_rne(float x) {
  unsigned u = __float_as_uint(x);
  unsigned r = (u + 0x7FFFu + ((u >> 16) & 1u)) >> 16;
  return (unsigned short)r;
}
DEV_INLINE void bf16_split(float x, unsigned short& hi, unsigned short& lo) {
  hi = bf16_rne(x);
  float hf = __uint_as_float(((unsigned)hi) << 16);
  lo = bf16_rne(x - hf);
}
DEV_INLINE float bf2f(unsigned short u) {
  return __uint_as_float(((unsigned)u) << 16);
}

#pragma clang diagnostic ignored "-Waddress-space-conversion"
DEV_INLINE void gload_lds16(const void* g, void* l) {
  __builtin_amdgcn_global_load_lds(
      (const __attribute__((address_space(1))) unsigned int*)g,
      (__attribute__((address_space(3))) unsigned int*)l, 16, 0, 0);
}

// ---------------- prep: transpose weights; bf16 hi/lo planes [N][K] -----------
__global__ __launch_bounds__(256)
void prep_kernel(const float* __restrict__ WA, const float* __restrict__ WB,
                 const float* __restrict__ WC, const float* __restrict__ WD,
                 const float* __restrict__ bA, const float* __restrict__ bB,
                 const float* __restrict__ bC, const float* __restrict__ bD,
                 const float* __restrict__ W2, const float* __restrict__ W3,
                 unsigned short* __restrict__ W1t_hi, unsigned short* __restrict__ W1t_lo,
                 unsigned short* __restrict__ W2t_hi, unsigned short* __restrict__ W2t_lo,
                 unsigned short* __restrict__ W3t_hi, unsigned short* __restrict__ W3t_lo,
                 float* __restrict__ biascat) {
  int i = blockIdx.x * 256 + threadIdx.x;
  if (i < 65536) {  // W1 planes: [z][j out][k in]
    int z = i >> 14, rem = i & 16383, j = rem >> 7, k = rem & 127;
    const float* W = (z == 0) ? WA : (z == 1) ? WB : (z == 2) ? WC : WD;
    unsigned short hi, lo;
    bf16_split(W[k * 128 + j], hi, lo);
    W1t_hi[i] = hi; W1t_lo[i] = lo;
  } else if (i < 196608) {  // W2t [256][512]
    int i2 = i - 65536, j = i2 >> 9, k = i2 & 511;
    unsigned short hi, lo;
    bf16_split(W2[k * 256 + j], hi, lo);
    W2t_hi[i2] = hi; W2t_lo[i2] = lo;
  } else if (i < 229376) {  // W3t [128][256]
    int i3 = i - 196608, j = i3 >> 8, k = i3 & 255;
    unsigned short hi, lo;
    bf16_split(W3[k * 128 + j], hi, lo);
    W3t_hi[i3] = hi; W3t_lo[i3] = lo;
  } else if (i < 229888) {
    int i4 = i - 229376, c = i4 >> 7, j = i4 & 127;
    const float* b = (c == 0) ? bA : (c == 1) ? bB : (c == 2) ? bC : bD;
    biascat[i4] = b[j];
  }
}

// ---------------- x -> bf16 cast ----------------------------------------------
__global__ __launch_bounds__(256)
void xcast_kernel(const float* __restrict__ x, unsigned short* __restrict__ xb, int total4) {
  int i = blockIdx.x * 256 + threadIdx.x;
  if (i >= total4) return;
  float4 v = ((const float4*)x)[i];
  ushort4 o;
  o.x = bf16_rne(v.x); o.y = bf16_rne(v.y); o.z = bf16_rne(v.z); o.w = bf16_rne(v.w);
  ((ushort4*)xb)[i] = o;
}

// ---------------- in-degree histogram ----------------------------------------
__global__ __launch_bounds__(256)
void hist_kernel(const int* __restrict__ ei, int* __restrict__ cnt, int E) {
  int e = blockIdx.x * 256 + threadIdx.x;
  if (e < E) atomicAdd(&cnt[ei[E + e]], 1);
}

// ---------------- 3-level exclusive scan -------------------------------------
__global__ __launch_bounds__(256)
void scan1_kernel(const int* __restrict__ cnt, int* __restrict__ local,
                  int* __restrict__ bsum, int n) {
  __shared__ int s[256];
  int tid = threadIdx.x;
  int i = blockIdx.x * 256 + tid;
  int v = (i < n) ? cnt[i] : 0;
  s[tid] = v;
  __syncthreads();
#pragma unroll
  for (int off = 1; off < 256; off <<= 1) {
    int t = (tid >= off) ? s[tid - off] : 0;
    __syncthreads();
    s[tid] += t;
    __syncthreads();
  }
  if (i < n) local[i] = s[tid] - v;
  if (tid == 255) bsum[blockIdx.x] = s[255];
}

__global__ __launch_bounds__(256)
void scan2_kernel(int* __restrict__ bsum, int nb) {
  __shared__ int s[256];
  int tid = threadIdx.x;
  int v = (tid < nb) ? bsum[tid] : 0;
  s[tid] = v;
  __syncthreads();
#pragma unroll
  for (int off = 1; off < 256; off <<= 1) {
    int t = (tid >= off) ? s[tid - off] : 0;
    __syncthreads();
    s[tid] += t;
    __syncthreads();
  }
  if (tid < nb) bsum[tid] = s[tid] - v;  // exclusive
}

__global__ __launch_bounds__(256)
void scan3_kernel(const int* __restrict__ local, const int* __restrict__ bsum,
                  int* __restrict__ rowptr, int* __restrict__ rowwork, int n, int E) {
  int i = blockIdx.x * 256 + threadIdx.x;
  if (i < n) {
    int rp = local[i] + bsum[blockIdx.x];
    rowptr[i] = rp;
    rowwork[i] = rp;
  }
  if (i == 0) rowptr[n] = E;
}

// ---------------- CSR fill (also writes src/dst per slot) ---------------------
__global__ __launch_bounds__(256)
void fill_kernel(const int* __restrict__ ei, int* __restrict__ rowwork,
                 int* __restrict__ csr, int* __restrict__ csr_src,
                 int* __restrict__ csr_dst, int E) {
  int e = blockIdx.x * 256 + threadIdx.x;
  if (e >= E) return;
  int d = ei[E + e];
  int pos = atomicAdd(&rowwork[d], 1);
  csr[pos] = e;
  csr_src[pos] = ei[e];
  csr_dst[pos] = d;
}

// ---------------- degrees from CSR (node-centric, fused rsqrt) ----------------
__global__ __launch_bounds__(256)
void degcsr_kernel(const int* __restrict__ rowptr, const int* __restrict__ csr,
                   const float* __restrict__ eattr, float* __restrict__ dis, int n) {
  int d = blockIdx.x * 256 + threadIdx.x;
  if (d >= n) return;
  int beg = rowptr[d], end = rowptr[d + 1];
  float s0 = 1.f, s1 = 1.f, s2 = 1.f, s3 = 1.f;  // self-loop weight 1
  for (int i = beg; i < end; ++i) {
    int e = csr[i];
    float4 w = ((const float4*)eattr)[e];
    s0 += w.x; s1 += w.y; s2 += w.z; s3 += w.w;
  }
  dis[d]         = 1.0f / sqrtf(s0);
  dis[n + d]     = 1.0f / sqrtf(s1);
  dis[2 * n + d] = 1.0f / sqrtf(s2);
  dis[3 * n + d] = 1.0f / sqrtf(s3);
  dis[4 * n + d] = 1.0f / sqrtf(1.0f + (float)(end - beg));
}

// ---------------- per-CSR-slot norms -------------------------------------------
__global__ __launch_bounds__(256)
void edgeprep_kernel(const int* __restrict__ csr, const int* __restrict__ csr_src,
                     const int* __restrict__ csr_dst, const float* __restrict__ eattr,
                     const float* __restrict__ dis, float4* __restrict__ norm4,
                     float* __restrict__ norm1, int n, int E) {
  int i = blockIdx.x * 256 + threadIdx.x;
  if (i >= E) return;
  int e = csr[i], s = csr_src[i], d = csr_dst[i];
  float4 w = ((const float4*)eattr)[e];
  float4 o;
  o.x = dis[s] * w.x * dis[d];
  o.y = dis[n + s] * w.y * dis[n + d];
  o.z = dis[2 * n + s] * w.z * dis[2 * n + d];
  o.w = dis[3 * n + s] * w.w * dis[3 * n + d];
  norm4[i] = o;
  norm1[i] = dis[4 * n + s] * dis[4 * n + d];
}

// ---------------- layer-1 aggregation on bf16 x; bf16 output -------------------
// 256 thr = 4 waves; wave w handles node blockIdx*4+w; lane t: cols 2t,2t+1
__global__ __launch_bounds__(256)
void agg4x_kernel(const unsigned short* __restrict__ xb,
                  unsigned short* __restrict__ xa,
                  const int* __restrict__ rowptr, const int* __restrict__ csr_src,
                  const float4* __restrict__ norm4, const float* __restrict__ dis,
                  int n, int npad) {
  int d = blockIdx.x * 4 + (threadIdx.x >> 6);
  if (d >= n) return;
  int t = threadIdx.x & 63;
  float dc0 = dis[d], dc1 = dis[n + d], dc2 = dis[2 * n + d], dc3 = dis[3 * n + d];
  const ushort2* x2 = (const ushort2*)xb;
  ushort2 xu = x2[(size_t)d * 64 + t];
  float xvx = bf2f(xu.x), xvy = bf2f(xu.y);
  float a0x = xvx * dc0 * dc0, a0y = xvy * dc0 * dc0;
  float a1x = xvx * dc1 * dc1, a1y = xvy * dc1 * dc1;
  float a2x = xvx * dc2 * dc2, a2y = xvy * dc2 * dc2;
  float a3x = xvx * dc3 * dc3, a3y = xvy * dc3 * dc3;
  int beg = rowptr[d], end = rowptr[d + 1];
  int i = beg;
  for (; i + 4 <= end; i += 4) {
    int s0 = csr_src[i], s1 = csr_src[i + 1], s2 = csr_src[i + 2], s3 = csr_src[i + 3];
    float4 m0 = norm4[i], m1 = norm4[i + 1], m2 = norm4[i + 2], m3 = norm4[i + 3];
    ushort2 u0 = x2[(size_t)s0 * 64 + t];
    ushort2 u1 = x2[(size_t)s1 * 64 + t];
    ushort2 u2 = x2[(size_t)s2 * 64 + t];
    ushort2 u3 = x2[(size_t)s3 * 64 + t];
    float h0x = bf2f(u0.x), h0y = bf2f(u0.y);
    float h1x = bf2f(u1.x), h1y = bf2f(u1.y);
    float h2x = bf2f(u2.x), h2y = bf2f(u2.y);
    float h3x = bf2f(u3.x), h3y = bf2f(u3.y);
    a0x += h0x * m0.x; a0y += h0y * m0.x;
    a1x += h0x * m0.y; a1y += h0y * m0.y;
    a2x += h0x * m0.z; a2y += h0y * m0.z;
    a3x += h0x * m0.w; a3y += h0y * m0.w;
    a0x += h1x * m1.x; a0y += h1y * m1.x;
    a1x += h1x * m1.y; a1y += h1y * m1.y;
    a2x += h1x * m1.z; a2y += h1y * m1.z;
    a3x += h1x * m1.w; a3y += h1y * m1.w;
    a0x += h2x * m2.x; a0y += h2y * m2.x;
    a1x += h2x * m2.y; a1y += h2y * m2.y;
    a2x += h2x * m2.z; a2y += h2y * m2.z;
    a3x += h2x * m2.w; a3y += h2y * m2.w;
    a0x += h3x * m3.x; a0y += h3y * m3.x;
    a1x += h3x * m3.y; a1y += h3y * m3.y;
    a2x += h3x * m3.z; a2y += h3y * m3.z;
    a3x += h3x * m3.w; a3y += h3y * m3.w;
  }
  for (; i < end; ++i) {
    int s = csr_src[i];
    float4 m = norm4[i];
    ushort2 u = x2[(size_t)s * 64 + t];
    float hx = bf2f(u.x), hy = bf2f(u.y);
    a0x += hx * m.x; a0y += hy * m.x;
    a1x += hx * m.y; a1y += hy * m.y;
    a2x += hx * m.z; a2y += hy * m.z;
    a3x += hx * m.w; a3y += hy * m.w;
  }
  size_t plane = (size_t)npad * 128;
  size_t base = (size_t)d * 128 + 2 * t;
  float vx[4] = {a0x, a1x, a2x, a3x};
  float vy[4] = {a0y, a1y, a2y, a3y};
#pragma unroll
  for (int z = 0; z < 4; ++z) {
    ushort2 ov; ov.x = bf16_rne(vx[z]); ov.y = bf16_rne(vy[z]);
    *(ushort2*)&xa[plane * z + base] = ov;
  }
}

// ---------------- MFMA GEMM: bf16 A (1 plane) x split-bf16 B (hi+lo) ----------
// LDS layout: [kchunk 0..3][row 0..127] of 16B units -> conflict-free b128 reads
// and global_load_lds-compatible staging (64 consecutive rows per instruction).
// MODE 1: bias+relu+bf16 out. MODE 2: bf16 out.
template <int MODE>
DEV_INLINE void gemm_mfma_body(const unsigned short* __restrict__ Ab, int K,
                               const unsigned short* __restrict__ Bh,
                               const unsigned short* __restrict__ Bl, int nTile0,
                               int ldc, int col0, unsigned short* __restrict__ Cb,
                               const float* __restrict__ bias, int M, int row0) {
  __shared__ __align__(16) unsigned short As[128 * 32];
  __shared__ __align__(16) unsigned short Bsh[128 * 32];
  __shared__ __align__(16) unsigned short Bsl[128 * 32];
  int tid = threadIdx.x;
  int w = tid >> 6, lane = tid & 63;
  int quad = lane >> 4, lrow = lane & 15;
  int wm = (w >> 1) * 64, wn = (w & 1) * 64;

  floatx4 zero4 = {0.f, 0.f, 0.f, 0.f};
  floatx4 acc[4][4];
#pragma unroll
  for (int i = 0; i < 4; ++i)
#pragma unroll
    for (int j = 0; j < 4; ++j) acc[i][j] = zero4;

  for (int k0 = 0; k0 < K; k0 += 32) {
    // staging: wave w stages k-chunk q=w; 2 instrs of 64 rows per array
#pragma unroll
    for (int half = 0; half < 2; ++half) {
      int row = half * 64 + lane;
      size_t ga = (size_t)(row0 + row) * K + k0 + w * 8;
      size_t gb = (size_t)(nTile0 + row) * K + k0 + w * 8;
      int lb = (w * 128 + half * 64) * 8;
      gload_lds16(Ab + ga, &As[lb]);
      gload_lds16(Bh + gb, &Bsh[lb]);
      gload_lds16(Bl + gb, &Bsl[lb]);
    }
    __syncthreads();
    bf16x8 ah[4];
#pragma unroll
    for (int i = 0; i < 4; ++i) {
      int off = (quad * 128 + wm + i * 16 + lrow) * 8;
      ah[i] = *(const bf16x8*)&As[off];
    }
#pragma unroll
    for (int j = 0; j < 4; ++j) {
      int off = (quad * 128 + wn + j * 16 + lrow) * 8;
      bf16x8 bh = *(const bf16x8*)&Bsh[off];
      bf16x8 bl = *(const bf16x8*)&Bsl[off];
#pragma unroll
      for (int i = 0; i < 4; ++i) {
        acc[i][j] = __builtin_amdgcn_mfma_f32_16x16x32_bf16(ah[i], bh, acc[i][j], 0, 0, 0);
        acc[i][j] = __builtin_amdgcn_mfma_f32_16x16x32_bf16(ah[i], bl, acc[i][j], 0, 0, 0);
      }
    }
    __syncthreads();
  }
  // epilogue: C/D layout col=lane&15, row=quad*4+reg
#pragma unroll
  for (int i = 0; i < 4; ++i) {
#pragma unroll
    for (int j = 0; j < 4; ++j) {
      int colL = wn + j * 16 + lrow;
#pragma unroll
      for (int r = 0; r < 4; ++r) {
        int row = row0 + wm + i * 16 + quad * 4 + r;
        if (row < M) {
          float v = acc[i][j][r];
          if (MODE == 1) v = fmaxf(v + bias[colL], 0.0f);
          Cb[(size_t)row * ldc + col0 + colL] = bf16_rne(v);
        }
      }
    }
  }
}

__global__ __launch_bounds__(256)
void gemm_l1_mfma(const unsigned short* __restrict__ xa,
                  const unsigned short* __restrict__ W1t_hi,
                  const unsigned short* __restrict__ W1t_lo,
                  const float* __restrict__ biascat,
                  unsigned short* __restrict__ h1, int M, int npad) {
  int z = blockIdx.z;
  size_t ap = (size_t)z * npad * 128;
  gemm_mfma_body<1>(xa + ap, 128, W1t_hi + z * 16384, W1t_lo + z * 16384, 0,
                    512, z * 128, h1, biascat + z * 128, M, blockIdx.x * 128);
}

__global__ __launch_bounds__(256)
void gemm_bf16out(const unsigned short* __restrict__ Ab, int K,
                  const unsigned short* __restrict__ Bh,
                  const unsigned short* __restrict__ Bl,
                  unsigned short* __restrict__ Cb, int ldc, int M) {
  gemm_mfma_body<2>(Ab, K, Bh, Bl, blockIdx.y * 128, ldc, blockIdx.y * 128,
                    Cb, nullptr, M, blockIdx.x * 128);
}

// ---------------- layers 2/3 aggregation: bf16 gather, 4-edge unroll ----------
// 256 thr = 4 waves; wave handles one node. OMODE 0: fp32 out, 1: bf16 out.
template <int VEC, bool RELU, int OMODE>
__global__ __launch_bounds__(256)
void agg1_kernel(const unsigned short* __restrict__ hb, float* __restrict__ out,
                 unsigned short* __restrict__ ob,
                 const int* __restrict__ rowptr, const int* __restrict__ csr_src,
                 const float* __restrict__ norm1, const float* __restrict__ dis1,
                 const float* __restrict__ bias, int n) {
  constexpr int DOUT = VEC * 64;
  int d = blockIdx.x * 4 + (threadIdx.x >> 6);
  if (d >= n) return;
  int t = threadIdx.x & 63;
  float dd = dis1[d];
  float acc[VEC];
  {
    float sw = dd * dd;
#pragma unroll
    for (int k = 0; k < VEC; ++k) acc[k] = bf2f(hb[(size_t)d * DOUT + t * VEC + k]) * sw;
  }
  int beg = rowptr[d], end = rowptr[d + 1];
  int i = beg;
  for (; i + 4 <= end; i += 4) {
    int s0 = csr_src[i], s1 = csr_src[i + 1], s2 = csr_src[i + 2], s3 = csr_src[i + 3];
    float m0 = norm1[i], m1 = norm1[i + 1], m2 = norm1[i + 2], m3 = norm1[i + 3];
    if (VEC == 4) {
      ushort4 u0 = *(const ushort4*)&hb[(size_t)s0 * DOUT + t * 4];
      ushort4 u1 = *(const ushort4*)&hb[(size_t)s1 * DOUT + t * 4];
      ushort4 u2 = *(const ushort4*)&hb[(size_t)s2 * DOUT + t * 4];
      ushort4 u3 = *(const ushort4*)&hb[(size_t)s3 * DOUT + t * 4];
      acc[0] += bf2f(u0.x) * m0; acc[1] += bf2f(u0.y) * m0;
      acc[2 % VEC] += bf2f(u0.z) * m0; acc[3 % VEC] += bf2f(u0.w) * m0;
      acc[0] += bf2f(u1.x) * m1; acc[1] += bf2f(u1.y) * m1;
      acc[2 % VEC] += bf2f(u1.z) * m1; acc[3 % VEC] += bf2f(u1.w) * m1;
      acc[0] += bf2f(u2.x) * m2; acc[1] += bf2f(u2.y) * m2;
      acc[2 % VEC] += bf2f(u2.z) * m2; acc[3 % VEC] += bf2f(u2.w) * m2;
      acc[0] += bf2f(u3.x) * m3; acc[1] += bf2f(u3.y) * m3;
      acc[2 % VEC] += bf2f(u3.z) * m3; acc[3 % VEC] += bf2f(u3.w) * m3;
    } else {
      ushort2 u0 = *(const ushort2*)&hb[(size_t)s0 * DOUT + t * 2];
      ushort2 u1 = *(const ushort2*)&hb[(size_t)s1 * DOUT + t * 2];
      ushort2 u2 = *(const ushort2*)&hb[(size_t)s2 * DOUT + t * 2];
      ushort2 u3 = *(const ushort2*)&hb[(size_t)s3 * DOUT + t * 2];
      acc[0] += bf2f(u0.x) * m0; acc[1 % VEC] += bf2f(u0.y) * m0;
      acc[0] += bf2f(u1.x) * m1; acc[1 % VEC] += bf2f(u1.y) * m1;
      acc[0] += bf2f(u2.x) * m2; acc[1 % VEC] += bf2f(u2.y) * m2;
      acc[0] += bf2f(u3.x) * m3; acc[1 % VEC] += bf2f(u3.y) * m3;
    }
  }
  for (; i < end; ++i) {
    int s = csr_src[i];
    float nrm = norm1[i];
    if (VEC == 4) {
      ushort4 u = *(const ushort4*)&hb[(size_t)s * DOUT + t * 4];
      acc[0] += bf2f(u.x) * nrm; acc[1] += bf2f(u.y) * nrm;
      acc[2 % VEC] += bf2f(u.z) * nrm; acc[3 % VEC] += bf2f(u.w) * nrm;
    } else {
      ushort2 u = *(const ushort2*)&hb[(size_t)s * DOUT + t * 2];
      acc[0] += bf2f(u.x) * nrm; acc[1 % VEC] += bf2f(u.y) * nrm;
    }
  }
#pragma unroll
  for (int k = 0; k < VEC; ++k) {
    float r = acc[k] + bias[t * VEC + k];
    if (RELU) r = fmaxf(r, 0.0f);
    if (OMODE == 1) {
      ob[(size_t)d * DOUT + t * VEC + k] = bf16_rne(r);
    } else {
      out[(size_t)d * DOUT + t * VEC + k] = r;
    }
  }
}

// ---------------- pooling: per-graph sum + max (encoded uint) -----------------
__global__ __launch_bounds__(128)
void pool_kernel(const float* __restrict__ h3, const int* __restrict__ batch,
                 float* __restrict__ gsum, unsigned* __restrict__ gmax, int n) {
  int c = threadIdx.x;
  int start = blockIdx.x * 32;
  int end = min(start + 32, n);
  int curg = -1;
  float s = 0.0f, m = -3.402823466e38f;
  for (int i = start; i < end; ++i) {
    int g = batch[i];
    if (g != curg) {
      if (curg >= 0) {
        atomicAdd(&gsum[curg * 128 + c], s);
        atomicMax(&gmax[curg * 128 + c], fencode(m));
      }
      curg = g; s = 0.0f; m = -3.402823466e38f;
    }
    float v = h3[(size_t)i * 128 + c];
    s += v;
    m = fmaxf(m, v);
  }
  if (curg >= 0) {
    atomicAdd(&gsum[curg * 128 + c], s);
    atomicMax(&gmax[curg * 128 + c], fencode(m));
  }
}

// ---------------- final MLP; per-graph counts via binary search ---------------
__global__ __launch_bounds__(512)
void mlp_kernel(const float* __restrict__ gsum, const unsigned* __restrict__ gmax,
                const int* __restrict__ batch, int n, const float* __restrict__ Wm1,
                const float* __restrict__ bm1, const float* __restrict__ Wm2,
                const float* __restrict__ bm2, float* __restrict__ out) {
  __shared__ float hid[64][8];
  int t = threadIdx.x;
  int gi = t >> 3, u = t & 7;
  auto lb = [&](int key) {
    int lo = 0, hi = n;
    while (lo < hi) {
      int mid = (lo + hi) >> 1;
      if (batch[mid] < key) lo = mid + 1; else hi = mid;
    }
    return lo;
  };
  int cnt = lb(gi + 1) - lb(gi);
  float inv = 1.0f / fmaxf((float)cnt, 1.0f);
  float s = bm1[u];
  for (int k = 0; k < 128; ++k) {
    float mean = gsum[gi * 128 + k] * inv;
    s += mean * Wm1[k * 8 + u];
  }
  for (int k = 0; k < 128; ++k) {
    float mx = (cnt > 0) ? fdecode(gmax[gi * 128 + k]) : 0.0f;
    s += mx * Wm1[(128 + k) * 8 + u];
  }
  hid[gi][u] = fmaxf(s, 0.0f);
  __syncthreads();
  if (t < 128) {
    int g2 = t >> 1, o = t & 1;
    float s2 = bm2[o];
#pragma unroll
    for (int uu = 0; uu < 8; ++uu) s2 += hid[g2][uu] * Wm2[uu * 2 + o];
    out[g2 * 2 + o] = s2;
  }
}

extern "C" void kernel_launch(void* const* d_in, const int* in_sizes, int n_in,
                              void* d_out, int out_size, void* d_ws, size_t ws_size,
                              hipStream_t stream) {
  const float* x     = (const float*)d_in[0];
  const int*   ei    = (const int*)d_in[1];
  const float* eattr = (const float*)d_in[2];
  const int*   batch = (const int*)d_in[3];
  const float* W1A = (const float*)d_in[4],  *b1A = (const float*)d_in[5];
  const float* W1B = (const float*)d_in[6],  *b1B = (const float*)d_in[7];
  const float* W1C = (const float*)d_in[8],  *b1C = (const float*)d_in[9];
  const float* W1D = (const float*)d_in[10], *b1D = (const float*)d_in[11];
  const float* W2  = (const float*)d_in[12], *b2  = (const float*)d_in[13];
  const float* W3  = (const float*)d_in[14], *b3  = (const float*)d_in[15];
  const float* Wm1 = (const float*)d_in[16], *bm1 = (const float*)d_in[17];
  const float* Wm2 = (const float*)d_in[18], *bm2 = (const float*)d_in[19];
  float* out = (float*)d_out;

  const int n = in_sizes[0] / 128;
  const int E = in_sizes[1] / 2;
  const int npad = (n + 127) & ~127;
  const int nmb = npad / 128;

  char* ws = (char*)d_ws;
  size_t off = 0;
  auto alloc = [&](size_t bytes) -> void* {
    void* p = ws + off;
    off += (bytes + 255) & ~(size_t)255;
    return p;
  };

  float*    dis     = (float*)alloc((size_t)5 * n * 4);
  int*      rowptr  = (int*)alloc(((size_t)n + 1) * 4);
  int*      rowwork = (int*)alloc((size_t)n * 4);
  int*      local   = (int*)alloc((size_t)n * 4);
  int*      bsum    = (int*)alloc(256 * 4);
  // ---- zero block start ----
  size_t zoff = off;
  int*      cnt     = (int*)alloc((size_t)n * 4);
  float*    gsum    = (float*)alloc(64 * 128 * 4);
  unsigned* gmax    = (unsigned*)alloc(64 * 128 * 4);
  size_t zbytes = off - zoff;
  // ---- zero block end ----
  int*      csr     = (int*)alloc((size_t)E * 4);
  int*      csr_src = (int*)alloc((size_t)E * 4);
  int*      csr_dst = (int*)alloc((size_t)E * 4);
  float4*   norm4   = (float4*)alloc((size_t)E * 16);
  float*    norm1   = (float*)alloc((size_t)E * 4);
  unsigned short* W1t_hi = (unsigned short*)alloc(65536 * 2);
  unsigned short* W1t_lo = (unsigned short*)alloc(65536 * 2);
  unsigned short* W2t_hi = (unsigned short*)alloc(131072 * 2);
  unsigned short* W2t_lo = (unsigned short*)alloc(131072 * 2);
  unsigned short* W3t_hi = (unsigned short*)alloc(32768 * 2);
  unsigned short* W3t_lo = (unsigned short*)alloc(32768 * 2);
  float*    biascat = (float*)alloc(512 * 4);
  unsigned short* xb   = (unsigned short*)alloc((size_t)npad * 128 * 2);
  unsigned short* bufA = (unsigned short*)alloc((size_t)npad * 512 * 2);  // xa / h2pre / h3pre
  unsigned short* bufB = (unsigned short*)alloc((size_t)npad * 512 * 2);  // h1 / h2+h3

  unsigned short* xa      = bufA;                     // 4 planes [npad,128] bf16
  unsigned short* h1      = bufB;                     // [npad,512] bf16
  unsigned short* h2pre_b = bufA;                     // [npad,256] bf16 (xa dead)
  unsigned short* h2      = bufB;                     // [npad,256] bf16 (h1 dead after gemm_l2)
  unsigned short* h3pre_b = bufA;                     // [npad,128] bf16 (h2pre dead)
  float*          h3      = (float*)(bufB + (size_t)npad * 256);  // [npad,128] fp32

  hipMemsetAsync(ws + zoff, 0, zbytes, stream);

  prep_kernel<<<(229888 + 255) / 256, 256, 0, stream>>>(
      W1A, W1B, W1C, W1D, b1A, b1B, b1C, b1D, W2, W3,
      W1t_hi, W1t_lo, W2t_hi, W2t_lo, W3t_hi, W3t_lo, biascat);
  xcast_kernel<<<((n * 32) + 255) / 256, 256, 0, stream>>>(x, xb, n * 32);

  int nb = (n + 255) / 256;
  hist_kernel<<<(E + 255) / 256, 256, 0, stream>>>(ei, cnt, E);
  scan1_kernel<<<nb, 256, 0, stream>>>(cnt, local, bsum, n);
  scan2_kernel<<<1, 256, 0, stream>>>(bsum, nb);
  scan3_kernel<<<nb, 256, 0, stream>>>(local, bsum, rowptr, rowwork, n, E);
  fill_kernel<<<(E + 255) / 256, 256, 0, stream>>>(ei, rowwork, csr, csr_src, csr_dst, E);
  degcsr_kernel<<<(n + 255) / 256, 256, 0, stream>>>(rowptr, csr, eattr, dis, n);
  edgeprep_kernel<<<(E + 255) / 256, 256, 0, stream>>>(csr, csr_src, csr_dst, eattr,
                                                       dis, norm4, norm1, n, E);

  int nodeblk = (n + 3) / 4;
  // layer 1
  agg4x_kernel<<<nodeblk, 256, 0, stream>>>(xb, xa, rowptr, csr_src, norm4, dis, n, npad);
  gemm_l1_mfma<<<dim3(nmb, 1, 4), 256, 0, stream>>>(xa, W1t_hi, W1t_lo, biascat, h1, n, npad);
  // layer 2
  gemm_bf16out<<<dim3(nmb, 2), 256, 0, stream>>>(h1, 512, W2t_hi, W2t_lo, h2pre_b, 256, n);
  agg1_kernel<4, true, 1><<<nodeblk, 256, 0, stream>>>(h2pre_b, nullptr, h2,
                                                       rowptr, csr_src, norm1,
                                                       dis + (size_t)4 * n, b2, n);
  // layer 3
  gemm_bf16out<<<dim3(nmb, 1), 256, 0, stream>>>(h2, 256, W3t_hi, W3t_lo, h3pre_b, 128, n);
  agg1_kernel<2, false, 0><<<nodeblk, 256, 0, stream>>>(h3pre_b, h3, nullptr,
                                                        rowptr, csr_src, norm1,
                                                        dis + (size_t)4 * n, b3, n);

  pool_kernel<<<(n + 31) / 32, 128, 0, stream>>>(h3, batch, gsum, gmax, n);
  mlp_kernel<<<1, 512, 0, stream>>>(gsum, gmax, batch, n, Wm1, bm1, Wm2, bm2, out);
}